// Round 12
// baseline (1597.884 us; speedup 1.0000x reference)
//
#include <hip/hip_runtime.h>
#include <math.h>

#define INV_SQRT1P 0.99999500003749968754f   // 1/sqrt(1+1e-5)
#define REMOVED  -2.0e38f
#define NEGINIT  -3.0e38f

static __device__ __forceinline__ float lrelu(float f){ return f >= 0.0f ? f : 0.2f*f; }

// ---------------- extract channels: feat (8,131,1024) -> rows [boff*1024..) (N,Cout) ----
__global__ void k_extract(const float* __restrict__ f, float* __restrict__ out, int c0, int Cout, int boff){
  int i = blockIdx.x*256 + threadIdx.x;
  int total = 8*Cout*1024;
  if (i >= total) return;
  int n  = i & 1023;
  int bc = i >> 10;
  int c  = bc % Cout;
  int b  = bc / Cout;
  out[((size_t)(((b+boff)<<10)+n))*Cout + c] = f[((size_t)(b*131 + c0 + c) << 10) + n];
}

// ---------------- extract transposed: feat (8,131,1024) -> XT (Cout,16384) ----------
__global__ void k_extractT(const float* __restrict__ f, float* __restrict__ XT, int c0, int Cout, int boff){
  int i = blockIdx.x*256 + threadIdx.x;
  int total = 8*Cout*1024;
  if (i >= total) return;
  int n  = i & 1023;
  int bc = i >> 10;
  int c  = bc % Cout;
  int b  = bc / Cout;
  XT[(size_t)c*16384 + (((b+boff)<<10)+n)] = f[((size_t)(b*131 + c0 + c) << 10) + n];
}

// ---------------- tiled transpose: X (16384,C) -> XT (C,16384), C multiple of 64 ------
__global__ __launch_bounds__(256) void k_tr(const float* __restrict__ X, float* __restrict__ XT, int C){
  __shared__ float t[64][65];
  int tx = threadIdx.x & 15, ty = threadIdx.x >> 4;
  int rb = blockIdx.y*64, cb = blockIdx.x*64;
  #pragma unroll
  for (int p=0;p<4;p++){
    int r = ty + p*16;
    float4 v = *(const float4*)(X + (size_t)(rb+r)*C + cb + tx*4);
    t[r][tx*4+0]=v.x; t[r][tx*4+1]=v.y; t[r][tx*4+2]=v.z; t[r][tx*4+3]=v.w;
  }
  __syncthreads();
  #pragma unroll
  for (int p=0;p<4;p++){
    int c = ty + p*16;
    float o[4] = {t[tx*4+0][c], t[tx*4+1][c], t[tx*4+2][c], t[tx*4+3][c]};
    *(float4*)(XT + (size_t)(cb+c)*16384 + rb + tx*4) = *(float4*)o;
  }
}

// ---------------- row sum of squares: x (16384,C) -> xx (16384) ----------------
__global__ void k_xx(const float* __restrict__ x, float* __restrict__ xx, int C){
  int r = blockIdx.x*256 + threadIdx.x;
  if (r >= 16384) return;
  const float* xr = x + (size_t)r*C;
  float s = 0.f;
  for (int c=0;c<C;c++) s += xr[c]*xr[c];
  xx[r] = s;
}

// ---------------- thin NT GEMM: 32 rows x 64 cols per block, 2x4/thread ----------------
__global__ __launch_bounds__(256) void k_gthin(
    const float* __restrict__ Am, const float* __restrict__ Bm, float* __restrict__ Om,
    int K, int ldo, int wmode, const float* __restrict__ p1, const float* __restrict__ p2, int ep)
{
  __shared__ float As[64][33];
  __shared__ float Bs[64][68];
  int tid = threadIdx.x;
  int tx = tid & 15, ty = tid >> 4;
  int rbase = blockIdx.y*32, cbase = blockIdx.x*64;
  float acc[2][4];
  #pragma unroll
  for (int i=0;i<2;i++){ acc[i][0]=0.f; acc[i][1]=0.f; acc[i][2]=0.f; acc[i][3]=0.f; }

  for (int c0=0; c0<K; c0+=64){
    int cw = K - c0; if (cw > 64) cw = 64;
    #pragma unroll
    for (int p=0; p<2; p++){
      int idx = p*256 + tid;
      int kq = idx & 15, row = idx >> 4;
      const float* src = Am + (size_t)(rbase+row)*K + c0 + kq*4;
      float4 v = {0.f,0.f,0.f,0.f};
      if (kq*4 + 4 <= cw) v = *(const float4*)src;
      else {
        if (kq*4+0 < cw) v.x = src[0];
        if (kq*4+1 < cw) v.y = src[1];
        if (kq*4+2 < cw) v.z = src[2];
        if (kq*4+3 < cw) v.w = src[3];
      }
      As[kq*4+0][row]=v.x; As[kq*4+1][row]=v.y; As[kq*4+2][row]=v.z; As[kq*4+3][row]=v.w;
    }
    #pragma unroll
    for (int p=0; p<4; p++){
      int idx = p*256 + tid;
      int kq = idx & 15, col = idx >> 4;
      int j = cbase + col;
      const float* src = (wmode > 0)
          ? ((j < wmode) ? Bm + (size_t)j*2*K + c0 + kq*4
                         : Bm + (size_t)(j-wmode)*2*K + K + c0 + kq*4)
          : Bm + (size_t)j*K + c0 + kq*4;
      float4 v = {0.f,0.f,0.f,0.f};
      if (kq*4 + 4 <= cw) v = *(const float4*)src;
      else {
        if (kq*4+0 < cw) v.x = src[0];
        if (kq*4+1 < cw) v.y = src[1];
        if (kq*4+2 < cw) v.z = src[2];
        if (kq*4+3 < cw) v.w = src[3];
      }
      int swb = (kq & 14) << 1;
      int cs = col ^ swb;
      Bs[kq*4+0][cs]=v.x; Bs[kq*4+1][cs]=v.y; Bs[kq*4+2][cs]=v.z; Bs[kq*4+3][cs]=v.w;
    }
    __syncthreads();
    for (int k=0;k<cw;k++){
      int sw = ((k>>3)&7)<<2;
      float a0 = As[k][ty*2], a1 = As[k][ty*2+1];
      float b[4];
      *(float4*)b = *(const float4*)&Bs[k][(tx*4) ^ sw];
      acc[0][0]+=a0*b[0]; acc[0][1]+=a0*b[1]; acc[0][2]+=a0*b[2]; acc[0][3]+=a0*b[3];
      acc[1][0]+=a1*b[0]; acc[1][1]+=a1*b[1]; acc[1][2]+=a1*b[2]; acc[1][3]+=a1*b[3];
    }
    __syncthreads();
  }
  #pragma unroll
  for (int i=0;i<2;i++){
    int r = rbase + ty*2 + i;
    float o[4];
    #pragma unroll
    for (int j=0;j<4;j++){
      int cc = cbase + tx*4 + j;
      float v = acc[i][j];
      if (ep == 1) v = lrelu(p1[cc]*v*INV_SQRT1P + p2[cc]);
      o[j] = v;
    }
    *(float4*)(Om + (size_t)r*ldo + cbase + tx*4) = *(float4*)o;
  }
}

// ---------------- fused distance + top-20 (1 wave per row) ----------------
// Computes the row's 1024 neg-distances on the fly from XT (C,16384) — no S buffer.
// dist(m) = 2*dot(x_n,x_m) - xx[n] - xx[m]; lane l owns m = 4l + 256jj + qq.
// Then: tau prefilter -> LDS compaction (u64 keys) -> bitonic / extract-max.
__global__ __launch_bounds__(64) void k_dtopk(const float* __restrict__ XT,
      const float* __restrict__ Xrm, const float* __restrict__ xx,
      int* __restrict__ idx, int C){
  int row = blockIdx.x;
  int b = row >> 10; int n = row & 1023;
  int l = threadIdx.x;
  const float* xxb = xx + (b<<10);
  float xn_n = xxb[n];

  float4 q[4];
  #pragma unroll
  for (int jj=0;jj<4;jj++){ q[jj].x=0.f; q[jj].y=0.f; q[jj].z=0.f; q[jj].w=0.f; }

  for (int kc=0; kc<C; kc+=32){
    int cw = C - kc; if (cw > 32) cw = 32;
    float xn[32];
    if (cw == 32){
      #pragma unroll
      for (int t=0;t<8;t++) *(float4*)&xn[t*4] = *(const float4*)(Xrm + (size_t)row*C + kc + t*4);
    } else {
      for (int t=0;t<cw;t++) xn[t] = Xrm[(size_t)row*C + kc + t];
    }
    const float* XTk = XT + (size_t)kc*16384 + ((size_t)b<<10);
    if (cw == 32){
      #pragma unroll
      for (int k=0;k<32;k++){
        float a = xn[k];
        const float4* p = (const float4*)(XTk + (size_t)k*16384);
        float4 v0 = p[l], v1 = p[l+64], v2 = p[l+128], v3 = p[l+192];
        q[0].x += a*v0.x; q[0].y += a*v0.y; q[0].z += a*v0.z; q[0].w += a*v0.w;
        q[1].x += a*v1.x; q[1].y += a*v1.y; q[1].z += a*v1.z; q[1].w += a*v1.w;
        q[2].x += a*v2.x; q[2].y += a*v2.y; q[2].z += a*v2.z; q[2].w += a*v2.w;
        q[3].x += a*v3.x; q[3].y += a*v3.y; q[3].z += a*v3.z; q[3].w += a*v3.w;
      }
    } else {
      for (int k=0;k<cw;k++){
        float a = xn[k];
        const float4* p = (const float4*)(XTk + (size_t)k*16384);
        float4 v0 = p[l], v1 = p[l+64], v2 = p[l+128], v3 = p[l+192];
        q[0].x += a*v0.x; q[0].y += a*v0.y; q[0].z += a*v0.z; q[0].w += a*v0.w;
        q[1].x += a*v1.x; q[1].y += a*v1.y; q[1].z += a*v1.z; q[1].w += a*v1.w;
        q[2].x += a*v2.x; q[2].y += a*v2.y; q[2].z += a*v2.z; q[2].w += a*v2.w;
        q[3].x += a*v3.x; q[3].y += a*v3.y; q[3].z += a*v3.z; q[3].w += a*v3.w;
      }
    }
  }
  // epilogue: neg_d
  const float4* xq = (const float4*)xxb;
  #pragma unroll
  for (int jj=0;jj<4;jj++){
    float4 xv = xq[l + 64*jj];
    q[jj].x = 2.f*q[jj].x - xn_n - xv.x;
    q[jj].y = 2.f*q[jj].y - xn_n - xv.y;
    q[jj].z = 2.f*q[jj].z - xn_n - xv.z;
    q[jj].w = 2.f*q[jj].w - xn_n - xv.w;
  }
  int out_base = row*20;

  // per-lane max of 16
  float lmax = fmaxf(fmaxf(fmaxf(q[0].x,q[0].y),fmaxf(q[0].z,q[0].w)),
               fmaxf(fmaxf(fmaxf(q[1].x,q[1].y),fmaxf(q[1].z,q[1].w)),
               fmaxf(fmaxf(fmaxf(q[2].x,q[2].y),fmaxf(q[2].z,q[2].w)),
                     fmaxf(fmaxf(q[3].x,q[3].y),fmaxf(q[3].z,q[3].w)))));

  // ascending bitonic sort of 64 lane maxima -> tau at lane 44 (20th largest)
  float sv = lmax;
  #pragma unroll
  for (int k=2; k<=64; k<<=1){
    #pragma unroll
    for (int j=k>>1; j>0; j>>=1){
      float o = __shfl_xor(sv, j, 64);
      bool a  = (l & k) == 0;
      bool bb = (l & j) == 0;
      sv = (a == bb) ? fminf(sv, o) : fmaxf(sv, o);
    }
  }
  float tau = __shfl(sv, 44, 64);

  float vv[16] = {q[0].x,q[0].y,q[0].z,q[0].w, q[1].x,q[1].y,q[1].z,q[1].w,
                  q[2].x,q[2].y,q[2].z,q[2].w, q[3].x,q[3].y,q[3].z,q[3].w};
  int cnt = 0;
  #pragma unroll
  for (int j=0;j<16;j++) cnt += (vv[j] >= tau) ? 1 : 0;
  int inc = cnt;
  #pragma unroll
  for (int off=1; off<64; off<<=1){
    int t = __shfl_up(inc, off, 64);
    inc += (l >= off) ? t : 0;
  }
  int Ns = __shfl(inc, 63, 64);

  __shared__ unsigned long long sl[128];

  if (Ns <= 128){
    sl[l] = 0ull; sl[64+l] = 0ull;
    __syncthreads();
    int slot = inc - cnt;
    #pragma unroll
    for (int j=0;j<16;j++){
      if (vv[j] >= tau){
        int m = 4*l + 64*(j & ~3) + (j & 3);
        unsigned int mv = __float_as_uint(vv[j]);
        mv = (mv & 0x80000000u) ? ~mv : (mv | 0x80000000u);
        sl[slot] = ((unsigned long long)mv << 10) | (unsigned)(1023 - m);
        slot++;
      }
    }
    __syncthreads();
    if (Ns <= 64){
      unsigned long long key = sl[l];
      #pragma unroll
      for (int k=2; k<=64; k<<=1){
        #pragma unroll
        for (int j=k>>1; j>0; j>>=1){
          unsigned long long o = __shfl_xor(key, j, 64);
          bool a  = (l & k) == 0;
          bool bb = (l & j) == 0;
          unsigned long long mx = key > o ? key : o;
          unsigned long long mn = key > o ? o : key;
          key = (a == bb) ? mx : mn;     // descending
        }
      }
      if (l < 20) idx[out_base + l] = 1023 - (int)(key & 1023ull);
    } else {
      unsigned long long c0 = sl[l], c1 = sl[64+l];
      for (int kk=0; kk<20; kk++){
        unsigned long long m = c0 > c1 ? c0 : c1;
        #pragma unroll
        for (int off=32; off>0; off>>=1){
          unsigned long long o = __shfl_xor(m, off, 64);
          m = o > m ? o : m;
        }
        c0 = (c0 == m) ? 0ull : c0;
        c1 = (c1 == m) ? 0ull : c1;
        if (l == 0) idx[out_base + kk] = 1023 - (int)(m & 1023ull);
      }
    }
  } else {
    for (int kk=0; kk<20; kk++){
      float bv = NEGINIT; int bi = 0x3fffffff;
      #pragma unroll
      for (int j=0;j<16;j++){
        int m = 4*l + 64*(j & ~3) + (j & 3);
        if (vv[j] > bv || (vv[j] == bv && m < bi)){ bv = vv[j]; bi = m; }
      }
      #pragma unroll
      for (int off=32; off>0; off>>=1){
        float ov = __shfl_xor(bv, off, 64);
        int   oi = __shfl_xor(bi, off, 64);
        if (ov > bv || (ov == bv && oi < bi)){ bv = ov; bi = oi; }
      }
      #pragma unroll
      for (int j=0;j<16;j++){
        int m = 4*l + 64*(j & ~3) + (j & 3);
        vv[j] = (m == bi) ? REMOVED : vv[j];
      }
      if (l == 0) idx[out_base + kk] = bi;
    }
  }
}

// ---------------- edge epilogue: gather Y1 at neighbors, +center, scale/bias/lrelu, max_k
__global__ void k_edge(const float* __restrict__ Y, const int* __restrict__ idx,
    const float* __restrict__ g, const float* __restrict__ bias,
    float* __restrict__ out, int O, int ldo, int ooff){
  int row = blockIdx.x; int o = threadIdx.x; int b = row >> 10;
  __shared__ int js[20];
  if (threadIdx.x < 20) js[threadIdx.x] = idx[row*20 + threadIdx.x];
  __syncthreads();
  int O2 = O*2;
  float y1c = Y[(size_t)row*O2 + o];
  float d   = Y[(size_t)row*O2 + O + o] - y1c;
  float sc  = g[o] * INV_SQRT1P;
  float bb  = bias[o];
  const float* Yb = Y + ((size_t)(b<<10))*O2;
  float best = -1e38f;
  #pragma unroll
  for (int k=0;k<20;k++){
    float f = sc * (Yb[(size_t)js[k]*O2 + o] + d) + bb;
    best = fmaxf(best, lrelu(f));
  }
  out[(size_t)row*ldo + ooff + o] = best;
}

// ---------------- attention (16 batches) ----------------
__global__ __launch_bounds__(1024) void k_mean(const float* __restrict__ emb, float* __restrict__ m){
  int b = blockIdx.x; int f = threadIdx.x & 127; int ny = threadIdx.x >> 7;
  const float* e = emb + ((size_t)(b<<10) + ny*128)*128 + f;
  float s = 0.f;
  for (int n=0;n<128;n++) s += e[n*128];
  __shared__ float red[8][128];
  red[ny][f] = s;
  __syncthreads();
  if (ny == 0){
    float t = 0.f;
    #pragma unroll
    for (int i=0;i<8;i++) t += red[i][f];
    m[b*128+f] = t * (1.0f/1024.0f);
  }
}

__global__ __launch_bounds__(128) void k_gc(const float* __restrict__ m, const float* __restrict__ att_w,
     float* __restrict__ gc){
  int b = blockIdx.x, g = threadIdx.x;
  __shared__ float mr[128];
  mr[g] = m[b*128+g];
  __syncthreads();
  float s = 0.f;
  for (int f=0; f<128; f++) s += mr[f]*att_w[f*128+g];
  gc[b*128+g] = tanhf(s);
}

__global__ __launch_bounds__(64) void k_sc(const float* __restrict__ emb, const float* __restrict__ gc,
     float* __restrict__ sc, float* __restrict__ attout){
  int row = blockIdx.x; int l = threadIdx.x; int b = row >> 10;
  const float* e  = emb + (size_t)row*128;
  const float* gb = gc + b*128;
  float p = e[l]*gb[l] + e[l+64]*gb[l+64];
  #pragma unroll
  for (int off=32; off>0; off>>=1) p += __shfl_xor(p, off, 64);
  if (l == 0){
    float s = 1.0f/(1.0f + expf(-p));
    sc[row] = s;
    attout[row] = s;
  }
}

__global__ __launch_bounds__(1024) void k_pool(const float* __restrict__ emb, const float* __restrict__ sc,
     float* __restrict__ ep){
  int b = blockIdx.x; int f = threadIdx.x & 127; int ny = threadIdx.x >> 7;
  const float* e  = emb + ((size_t)(b<<10) + ny*128)*128 + f;
  const float* sb = sc + (b<<10) + ny*128;
  float s = 0.f;
  for (int n=0;n<128;n++) s += e[n*128]*sb[n];
  __shared__ float red[8][128];
  red[ny][f] = s;
  __syncthreads();
  if (ny == 0){
    float t = 0.f;
    #pragma unroll
    for (int i=0;i<8;i++) t += red[i][f];
    ep[b*128+f] = t;
  }
}

// ---------------- tensor network scoring ----------------
__global__ __launch_bounds__(256) void k_tnet(const float* __restrict__ e1, const float* __restrict__ e2,
    const float* __restrict__ tn_w, const float* __restrict__ tn_wb, const float* __restrict__ tn_bias,
    float* __restrict__ tsout){
  int b = blockIdx.x; int t = threadIdx.x; int tt = t & 15; int fs = t >> 4;
  __shared__ float E1[128], E2[128], red[16][17];
  if (t < 128){ E1[t] = e1[b*128+t]; E2[t] = e2[b*128+t]; }
  __syncthreads();
  float acc = 0.f;
  for (int f = fs*8; f < fs*8+8; f++){
    const float* tw = tn_w + f*128*16 + tt;
    float partial = 0.f;
    for (int g=0; g<128; g++) partial += E2[g]*tw[g*16];
    acc += E1[f]*partial;
  }
  red[fs][tt] = acc;
  __syncthreads();
  if (t < 16){
    float s = 0.f;
    #pragma unroll
    for (int i=0;i<16;i++) s += red[i][t];
    float acc2 = 0.f;
    for (int c=0;c<128;c++) acc2 += tn_wb[t*256+c]*E1[c] + tn_wb[t*256+128+c]*E2[c];
    float v = s + acc2 + tn_bias[t];
    tsout[b*16+t] = v > 0.f ? v : 0.f;
  }
}

__global__ __launch_bounds__(128) void k_score2(const float* __restrict__ ts,
   const float* __restrict__ fc1_w, const float* __restrict__ fc1_b,
   const float* __restrict__ sc_w, const float* __restrict__ sc_b, float* __restrict__ out){
  int t = threadIdx.x; int b = t >> 4, i = t & 15;
  __shared__ float h2[8][17];
  float a = 0.f;
  #pragma unroll
  for (int k=0;k<16;k++) a += ts[b*16+k]*fc1_w[i*16+k];
  a += fc1_b[i];
  h2[b][i] = a > 0.f ? a : 0.f;
  __syncthreads();
  if (t < 8){
    float s = 0.f;
    #pragma unroll
    for (int k=0;k<16;k++) s += h2[t][k]*sc_w[k];
    s += sc_b[0];
    out[t] = 1.0f/(1.0f + expf(-s));
  }
}

extern "C" void kernel_launch(void* const* d_in, const int* in_sizes, int n_in,
                              void* d_out, int out_size, void* d_ws, size_t ws_size,
                              hipStream_t stream){
  const float* f1  = (const float*)d_in[0];
  const float* f2  = (const float*)d_in[1];
  const float* sw1 = (const float*)d_in[2];  const float* sg1 = (const float*)d_in[3];  const float* sb1 = (const float*)d_in[4];
  const float* fw1 = (const float*)d_in[5];  const float* fg1 = (const float*)d_in[6];  const float* fb1 = (const float*)d_in[7];
  const float* sw2 = (const float*)d_in[8];  const float* sg2 = (const float*)d_in[9];  const float* sb2 = (const float*)d_in[10];
  const float* fw2 = (const float*)d_in[11]; const float* fg2 = (const float*)d_in[12]; const float* fb2 = (const float*)d_in[13];
  const float* sw3 = (const float*)d_in[14]; const float* sg3 = (const float*)d_in[15]; const float* sb3 = (const float*)d_in[16];
  const float* fw3 = (const float*)d_in[17]; const float* fg3 = (const float*)d_in[18]; const float* fb3 = (const float*)d_in[19];
  const float* ew  = (const float*)d_in[20]; const float* eg  = (const float*)d_in[21]; const float* eb  = (const float*)d_in[22];
  const float* att_w   = (const float*)d_in[23];
  const float* tn_w    = (const float*)d_in[24];
  const float* tn_wb   = (const float*)d_in[25];
  const float* tn_bias = (const float*)d_in[26];
  const float* fc1_w   = (const float*)d_in[27];
  const float* fc1_b   = (const float*)d_in[28];
  const float* sc_w    = (const float*)d_in[29];
  const float* sc_b    = (const float*)d_in[30];

  float* W    = (float*)d_ws;
  float* T0   = W;                  // 2,097,152  (16384 x <=128)
  float* T1   = W + 2097152;        // 2,097,152
  float* X3S3 = W + 4194304;        // 4,194,304  (16384 x 256)
  float* EMB  = W + 8388608;        // 2,097,152  (16384 x 128)
  float* XTb  = W + 10485760;       // 2,097,152  (<=128 x 16384)
  float* xx   = W + 12582912;       // 16384
  float* mb   = W + 12599296;       // 2048
  float* gcb  = W + 12601344;       // 2048
  float* scb  = W + 12603392;       // 16384
  float* ep   = W + 12619776;       // 2048
  float* tsb  = W + 12621824;       // 128
  int*   idxb = (int*)(W + 12621952); // 327680 ints
  float* REG  = W + 12949632;       // Y region (<= 4,194,304)

  (void)ws_size;
  float* out = (float*)d_out;

  auto edge = [&](const float* xin, int C, int O,
                  const float* w, const float* g, const float* bb,
                  float* xout, int ldo, int ooff, bool haveXT){
    k_xx<<<64, 256, 0, stream>>>(xin, xx, C);
    if (!haveXT)
      k_tr<<<dim3(C/64, 256), 256, 0, stream>>>(xin, XTb, C);
    k_dtopk<<<16384, 64, 0, stream>>>(XTb, xin, xx, idxb, C);
    k_gthin<<<dim3(2*O/64, 512, 1), 256, 0, stream>>>(xin, w, REG, C, 2*O,
          O, nullptr, nullptr, 0);
    k_edge<<<16384, O, 0, stream>>>(REG, idxb, g, bb, xout, O, ldo, ooff);
  };

  // xyz path (both point clouds as batches 0-7 / 8-15); XT comes free from input layout
  k_extract<<<(8*3*1024+255)/256, 256, 0, stream>>>(f1, T0, 0, 3, 0);
  k_extract<<<(8*3*1024+255)/256, 256, 0, stream>>>(f2, T0, 0, 3, 8);
  k_extractT<<<(8*3*1024+255)/256, 256, 0, stream>>>(f1, XTb, 0, 3, 0);
  k_extractT<<<(8*3*1024+255)/256, 256, 0, stream>>>(f2, XTb, 0, 3, 8);
  edge(T0, 3,   64, sw1, sg1, sb1, T1, 64, 0, true);
  edge(T1, 64,  64, sw2, sg2, sb2, T0, 64, 0, false);
  edge(T0, 64, 128, sw3, sg3, sb3, X3S3, 256, 0, false);    // x3 -> cols 0..127
  // sem path
  k_extract<<<(8*128*1024+255)/256, 256, 0, stream>>>(f1, T0, 3, 128, 0);
  k_extract<<<(8*128*1024+255)/256, 256, 0, stream>>>(f2, T0, 3, 128, 8);
  k_extractT<<<(8*128*1024+255)/256, 256, 0, stream>>>(f1, XTb, 3, 128, 0);
  k_extractT<<<(8*128*1024+255)/256, 256, 0, stream>>>(f2, XTb, 3, 128, 8);
  edge(T0, 128, 64, fw1, fg1, fb1, T1, 64, 0, true);
  edge(T1, 64,  64, fw2, fg2, fb2, T0, 64, 0, false);
  edge(T0, 64, 128, fw3, fg3, fb3, X3S3, 256, 128, false);  // s3 -> cols 128..255
  // combine: emb = lrelu(eg * (X3S3 @ ew^T)/sqrt(1+eps) + eb)
  k_gthin<<<dim3(2, 512, 1), 256, 0, stream>>>(X3S3, ew, EMB, 256, 128,
        0, eg, eb, 1);
  // attention over all 16 batches
  k_mean<<<16, 1024, 0, stream>>>(EMB, mb);
  k_gc<<<16, 128, 0, stream>>>(mb, att_w, gcb);
  k_sc<<<16384, 64, 0, stream>>>(EMB, gcb, scb, out + 8);
  k_pool<<<16, 1024, 0, stream>>>(EMB, scb, ep);

  k_tnet<<<8, 256, 0, stream>>>(ep, ep + 1024, tn_w, tn_wb, tn_bias, tsb);
  k_score2<<<1, 128, 0, stream>>>(tsb, fc1_w, fc1_b, sc_w, sc_b, out);
}

// Round 13
// 827.406 us; speedup vs baseline: 1.9312x; 1.9312x over previous
//
#include <hip/hip_runtime.h>
#include <math.h>

#define INV_SQRT1P 0.99999500003749968754f   // 1/sqrt(1+1e-5)
#define REMOVED  -2.0e38f
#define NEGINIT  -3.0e38f

static __device__ __forceinline__ float lrelu(float f){ return f >= 0.0f ? f : 0.2f*f; }

// ---------------- extract channels: feat (8,131,1024) -> rows [boff*1024..) (N,Cout) ----
__global__ void k_extract(const float* __restrict__ f, float* __restrict__ out, int c0, int Cout, int boff){
  int i = blockIdx.x*256 + threadIdx.x;
  int total = 8*Cout*1024;
  if (i >= total) return;
  int n  = i & 1023;
  int bc = i >> 10;
  int c  = bc % Cout;
  int b  = bc / Cout;
  out[((size_t)(((b+boff)<<10)+n))*Cout + c] = f[((size_t)(b*131 + c0 + c) << 10) + n];
}

// ---------------- extract transposed: feat (8,131,1024) -> XT (Cout,16384) ----------
__global__ void k_extractT(const float* __restrict__ f, float* __restrict__ XT, int c0, int Cout, int boff){
  int i = blockIdx.x*256 + threadIdx.x;
  int total = 8*Cout*1024;
  if (i >= total) return;
  int n  = i & 1023;
  int bc = i >> 10;
  int c  = bc % Cout;
  int b  = bc / Cout;
  XT[(size_t)c*16384 + (((b+boff)<<10)+n)] = f[((size_t)(b*131 + c0 + c) << 10) + n];
}

// ---------------- tiled transpose: X (16384,C) -> XT (C,16384), C multiple of 64 ------
__global__ __launch_bounds__(256) void k_tr(const float* __restrict__ X, float* __restrict__ XT, int C){
  __shared__ float t[64][65];
  int tx = threadIdx.x & 15, ty = threadIdx.x >> 4;
  int rb = blockIdx.y*64, cb = blockIdx.x*64;
  #pragma unroll
  for (int p=0;p<4;p++){
    int r = ty + p*16;
    float4 v = *(const float4*)(X + (size_t)(rb+r)*C + cb + tx*4);
    t[r][tx*4+0]=v.x; t[r][tx*4+1]=v.y; t[r][tx*4+2]=v.z; t[r][tx*4+3]=v.w;
  }
  __syncthreads();
  #pragma unroll
  for (int p=0;p<4;p++){
    int c = ty + p*16;
    float o[4] = {t[tx*4+0][c], t[tx*4+1][c], t[tx*4+2][c], t[tx*4+3][c]};
    *(float4*)(XT + (size_t)(cb+c)*16384 + rb + tx*4) = *(float4*)o;
  }
}

// ---------------- row sum of squares: x (16384,C) -> xx (16384) ----------------
__global__ void k_xx(const float* __restrict__ x, float* __restrict__ xx, int C){
  int r = blockIdx.x*256 + threadIdx.x;
  if (r >= 16384) return;
  const float* xr = x + (size_t)r*C;
  float s = 0.f;
  for (int c=0;c<C;c++) s += xr[c]*xr[c];
  xx[r] = s;
}

// ---------------- thin NT GEMM: 32 rows x 64 cols per block, 2x4/thread ----------------
__global__ __launch_bounds__(256) void k_gthin(
    const float* __restrict__ Am, const float* __restrict__ Bm, float* __restrict__ Om,
    int K, int ldo, int wmode, const float* __restrict__ p1, const float* __restrict__ p2, int ep)
{
  __shared__ float As[64][33];
  __shared__ float Bs[64][68];
  int tid = threadIdx.x;
  int tx = tid & 15, ty = tid >> 4;
  int rbase = blockIdx.y*32, cbase = blockIdx.x*64;
  float acc[2][4];
  #pragma unroll
  for (int i=0;i<2;i++){ acc[i][0]=0.f; acc[i][1]=0.f; acc[i][2]=0.f; acc[i][3]=0.f; }

  for (int c0=0; c0<K; c0+=64){
    int cw = K - c0; if (cw > 64) cw = 64;
    #pragma unroll
    for (int p=0; p<2; p++){
      int idx = p*256 + tid;
      int kq = idx & 15, row = idx >> 4;
      const float* src = Am + (size_t)(rbase+row)*K + c0 + kq*4;
      float4 v = {0.f,0.f,0.f,0.f};
      if (kq*4 + 4 <= cw) v = *(const float4*)src;
      else {
        if (kq*4+0 < cw) v.x = src[0];
        if (kq*4+1 < cw) v.y = src[1];
        if (kq*4+2 < cw) v.z = src[2];
        if (kq*4+3 < cw) v.w = src[3];
      }
      As[kq*4+0][row]=v.x; As[kq*4+1][row]=v.y; As[kq*4+2][row]=v.z; As[kq*4+3][row]=v.w;
    }
    #pragma unroll
    for (int p=0; p<4; p++){
      int idx = p*256 + tid;
      int kq = idx & 15, col = idx >> 4;
      int j = cbase + col;
      const float* src = (wmode > 0)
          ? ((j < wmode) ? Bm + (size_t)j*2*K + c0 + kq*4
                         : Bm + (size_t)(j-wmode)*2*K + K + c0 + kq*4)
          : Bm + (size_t)j*K + c0 + kq*4;
      float4 v = {0.f,0.f,0.f,0.f};
      if (kq*4 + 4 <= cw) v = *(const float4*)src;
      else {
        if (kq*4+0 < cw) v.x = src[0];
        if (kq*4+1 < cw) v.y = src[1];
        if (kq*4+2 < cw) v.z = src[2];
        if (kq*4+3 < cw) v.w = src[3];
      }
      int swb = (kq & 14) << 1;
      int cs = col ^ swb;
      Bs[kq*4+0][cs]=v.x; Bs[kq*4+1][cs]=v.y; Bs[kq*4+2][cs]=v.z; Bs[kq*4+3][cs]=v.w;
    }
    __syncthreads();
    for (int k=0;k<cw;k++){
      int sw = ((k>>3)&7)<<2;
      float a0 = As[k][ty*2], a1 = As[k][ty*2+1];
      float b[4];
      *(float4*)b = *(const float4*)&Bs[k][(tx*4) ^ sw];
      acc[0][0]+=a0*b[0]; acc[0][1]+=a0*b[1]; acc[0][2]+=a0*b[2]; acc[0][3]+=a0*b[3];
      acc[1][0]+=a1*b[0]; acc[1][1]+=a1*b[1]; acc[1][2]+=a1*b[2]; acc[1][3]+=a1*b[3];
    }
    __syncthreads();
  }
  #pragma unroll
  for (int i=0;i<2;i++){
    int r = rbase + ty*2 + i;
    float o[4];
    #pragma unroll
    for (int j=0;j<4;j++){
      int cc = cbase + tx*4 + j;
      float v = acc[i][j];
      if (ep == 1) v = lrelu(p1[cc]*v*INV_SQRT1P + p2[cc]);
      o[j] = v;
    }
    *(float4*)(Om + (size_t)r*ldo + cbase + tx*4) = *(float4*)o;
  }
}

// ---------------- fused distance + top-20, 4 rows per wave ----------------
// Lane l owns cols m = 4l + 256jj + qq for each of the wave's 4 rows (same batch).
// Per k-step: 4 coalesced float4 XT loads shared by 4 rows -> 64 FMAs/lane.
// No dynamic array indexing anywhere (no scratch spill). Selection = proven
// tau-prefilter + bitonic, run serially per row.
__global__ __launch_bounds__(64) void k_dtopk4(const float* __restrict__ XT,
      const float* __restrict__ Xrm, const float* __restrict__ xx,
      int* __restrict__ idx, int C){
  int r0 = blockIdx.x << 2;          // 4 rows, same batch (1024 % 4 == 0)
  int b  = r0 >> 10;
  int l  = threadIdx.x;
  const float* xxb = xx + (b<<10);
  const float* XTb = XT + ((size_t)b<<10);

  float4 acc[4][4];
  #pragma unroll
  for (int i=0;i<4;i++){
    #pragma unroll
    for (int jj=0;jj<4;jj++){ acc[i][jj].x=0.f; acc[i][jj].y=0.f; acc[i][jj].z=0.f; acc[i][jj].w=0.f; }
  }

  int nkq = (C+3) >> 2;
  for (int kq=0; kq<nkq; kq++){
    float xn[4][4];
    #pragma unroll
    for (int i=0;i<4;i++){
      const float* Xr = Xrm + (size_t)(r0+i)*C;
      #pragma unroll
      for (int t=0;t<4;t++){
        int k = kq*4+t;
        xn[i][t] = (k < C) ? Xr[k] : 0.f;
      }
    }
    #pragma unroll
    for (int t=0;t<4;t++){
      int k = kq*4+t;
      int kc = (k < C) ? k : (C-1);
      const float4* p = (const float4*)(XTb + (size_t)kc*16384);
      float4 v0 = p[l], v1 = p[l+64], v2 = p[l+128], v3 = p[l+192];
      #pragma unroll
      for (int i=0;i<4;i++){
        float a = xn[i][t];
        acc[i][0].x += a*v0.x; acc[i][0].y += a*v0.y; acc[i][0].z += a*v0.z; acc[i][0].w += a*v0.w;
        acc[i][1].x += a*v1.x; acc[i][1].y += a*v1.y; acc[i][1].z += a*v1.z; acc[i][1].w += a*v1.w;
        acc[i][2].x += a*v2.x; acc[i][2].y += a*v2.y; acc[i][2].z += a*v2.z; acc[i][2].w += a*v2.w;
        acc[i][3].x += a*v3.x; acc[i][3].y += a*v3.y; acc[i][3].z += a*v3.z; acc[i][3].w += a*v3.w;
      }
    }
  }

  // xx[m] float4s — shared by all 4 rows
  const float4* xq = (const float4*)xxb;
  float4 xv0 = xq[l], xv1 = xq[l+64], xv2 = xq[l+128], xv3 = xq[l+192];

  __shared__ unsigned long long sl[128];

  #pragma unroll
  for (int i=0;i<4;i++){
    int n = (r0 + i) & 1023;
    float xn_n = xxb[n];
    float4 q[4];
    q[0].x = 2.f*acc[i][0].x - xn_n - xv0.x; q[0].y = 2.f*acc[i][0].y - xn_n - xv0.y;
    q[0].z = 2.f*acc[i][0].z - xn_n - xv0.z; q[0].w = 2.f*acc[i][0].w - xn_n - xv0.w;
    q[1].x = 2.f*acc[i][1].x - xn_n - xv1.x; q[1].y = 2.f*acc[i][1].y - xn_n - xv1.y;
    q[1].z = 2.f*acc[i][1].z - xn_n - xv1.z; q[1].w = 2.f*acc[i][1].w - xn_n - xv1.w;
    q[2].x = 2.f*acc[i][2].x - xn_n - xv2.x; q[2].y = 2.f*acc[i][2].y - xn_n - xv2.y;
    q[2].z = 2.f*acc[i][2].z - xn_n - xv2.z; q[2].w = 2.f*acc[i][2].w - xn_n - xv2.w;
    q[3].x = 2.f*acc[i][3].x - xn_n - xv3.x; q[3].y = 2.f*acc[i][3].y - xn_n - xv3.y;
    q[3].z = 2.f*acc[i][3].z - xn_n - xv3.z; q[3].w = 2.f*acc[i][3].w - xn_n - xv3.w;

    int out_base = (r0 + i)*20;

    float lmax = fmaxf(fmaxf(fmaxf(q[0].x,q[0].y),fmaxf(q[0].z,q[0].w)),
                 fmaxf(fmaxf(fmaxf(q[1].x,q[1].y),fmaxf(q[1].z,q[1].w)),
                 fmaxf(fmaxf(fmaxf(q[2].x,q[2].y),fmaxf(q[2].z,q[2].w)),
                       fmaxf(fmaxf(q[3].x,q[3].y),fmaxf(q[3].z,q[3].w)))));

    float sv = lmax;
    #pragma unroll
    for (int k=2; k<=64; k<<=1){
      #pragma unroll
      for (int j=k>>1; j>0; j>>=1){
        float o = __shfl_xor(sv, j, 64);
        bool a  = (l & k) == 0;
        bool bb = (l & j) == 0;
        sv = (a == bb) ? fminf(sv, o) : fmaxf(sv, o);
      }
    }
    float tau = __shfl(sv, 44, 64);

    float vv[16] = {q[0].x,q[0].y,q[0].z,q[0].w, q[1].x,q[1].y,q[1].z,q[1].w,
                    q[2].x,q[2].y,q[2].z,q[2].w, q[3].x,q[3].y,q[3].z,q[3].w};
    int cnt = 0;
    #pragma unroll
    for (int j=0;j<16;j++) cnt += (vv[j] >= tau) ? 1 : 0;
    int inc = cnt;
    #pragma unroll
    for (int off=1; off<64; off<<=1){
      int t = __shfl_up(inc, off, 64);
      inc += (l >= off) ? t : 0;
    }
    int Ns = __shfl(inc, 63, 64);

    if (Ns <= 128){
      sl[l] = 0ull; sl[64+l] = 0ull;
      __syncthreads();
      int slot = inc - cnt;
      #pragma unroll
      for (int j=0;j<16;j++){
        if (vv[j] >= tau){
          int m = 4*l + 64*(j & ~3) + (j & 3);
          unsigned int mv = __float_as_uint(vv[j]);
          mv = (mv & 0x80000000u) ? ~mv : (mv | 0x80000000u);
          sl[slot] = ((unsigned long long)mv << 10) | (unsigned)(1023 - m);
          slot++;
        }
      }
      __syncthreads();
      if (Ns <= 64){
        unsigned long long key = sl[l];
        #pragma unroll
        for (int k=2; k<=64; k<<=1){
          #pragma unroll
          for (int j=k>>1; j>0; j>>=1){
            unsigned long long o = __shfl_xor(key, j, 64);
            bool a  = (l & k) == 0;
            bool bb = (l & j) == 0;
            unsigned long long mx = key > o ? key : o;
            unsigned long long mn = key > o ? o : key;
            key = (a == bb) ? mx : mn;     // descending
          }
        }
        if (l < 20) idx[out_base + l] = 1023 - (int)(key & 1023ull);
      } else {
        unsigned long long c0 = sl[l], c1 = sl[64+l];
        for (int kk=0; kk<20; kk++){
          unsigned long long m = c0 > c1 ? c0 : c1;
          #pragma unroll
          for (int off=32; off>0; off>>=1){
            unsigned long long o = __shfl_xor(m, off, 64);
            m = o > m ? o : m;
          }
          c0 = (c0 == m) ? 0ull : c0;
          c1 = (c1 == m) ? 0ull : c1;
          if (l == 0) idx[out_base + kk] = 1023 - (int)(m & 1023ull);
        }
      }
      __syncthreads();
    } else {
      for (int kk=0; kk<20; kk++){
        float bv = NEGINIT; int bi = 0x3fffffff;
        #pragma unroll
        for (int j=0;j<16;j++){
          int m = 4*l + 64*(j & ~3) + (j & 3);
          if (vv[j] > bv || (vv[j] == bv && m < bi)){ bv = vv[j]; bi = m; }
        }
        #pragma unroll
        for (int off=32; off>0; off>>=1){
          float ov = __shfl_xor(bv, off, 64);
          int   oi = __shfl_xor(bi, off, 64);
          if (ov > bv || (ov == bv && oi < bi)){ bv = ov; bi = oi; }
        }
        #pragma unroll
        for (int j=0;j<16;j++){
          int m = 4*l + 64*(j & ~3) + (j & 3);
          vv[j] = (m == bi) ? REMOVED : vv[j];
        }
        if (l == 0) idx[out_base + kk] = bi;
      }
    }
  }
}

// ---------------- edge epilogue: gather Y1 at neighbors, +center, scale/bias/lrelu, max_k
__global__ void k_edge(const float* __restrict__ Y, const int* __restrict__ idx,
    const float* __restrict__ g, const float* __restrict__ bias,
    float* __restrict__ out, int O, int ldo, int ooff){
  int row = blockIdx.x; int o = threadIdx.x; int b = row >> 10;
  __shared__ int js[20];
  if (threadIdx.x < 20) js[threadIdx.x] = idx[row*20 + threadIdx.x];
  __syncthreads();
  int O2 = O*2;
  float y1c = Y[(size_t)row*O2 + o];
  float d   = Y[(size_t)row*O2 + O + o] - y1c;
  float sc  = g[o] * INV_SQRT1P;
  float bb  = bias[o];
  const float* Yb = Y + ((size_t)(b<<10))*O2;
  float best = -1e38f;
  #pragma unroll
  for (int k=0;k<20;k++){
    float f = sc * (Yb[(size_t)js[k]*O2 + o] + d) + bb;
    best = fmaxf(best, lrelu(f));
  }
  out[(size_t)row*ldo + ooff + o] = best;
}

// ---------------- attention (16 batches) ----------------
__global__ __launch_bounds__(1024) void k_mean(const float* __restrict__ emb, float* __restrict__ m){
  int b = blockIdx.x; int f = threadIdx.x & 127; int ny = threadIdx.x >> 7;
  const float* e = emb + ((size_t)(b<<10) + ny*128)*128 + f;
  float s = 0.f;
  for (int n=0;n<128;n++) s += e[n*128];
  __shared__ float red[8][128];
  red[ny][f] = s;
  __syncthreads();
  if (ny == 0){
    float t = 0.f;
    #pragma unroll
    for (int i=0;i<8;i++) t += red[i][f];
    m[b*128+f] = t * (1.0f/1024.0f);
  }
}

__global__ __launch_bounds__(128) void k_gc(const float* __restrict__ m, const float* __restrict__ att_w,
     float* __restrict__ gc){
  int b = blockIdx.x, g = threadIdx.x;
  __shared__ float mr[128];
  mr[g] = m[b*128+g];
  __syncthreads();
  float s = 0.f;
  for (int f=0; f<128; f++) s += mr[f]*att_w[f*128+g];
  gc[b*128+g] = tanhf(s);
}

__global__ __launch_bounds__(64) void k_sc(const float* __restrict__ emb, const float* __restrict__ gc,
     float* __restrict__ sc, float* __restrict__ attout){
  int row = blockIdx.x; int l = threadIdx.x; int b = row >> 10;
  const float* e  = emb + (size_t)row*128;
  const float* gb = gc + b*128;
  float p = e[l]*gb[l] + e[l+64]*gb[l+64];
  #pragma unroll
  for (int off=32; off>0; off>>=1) p += __shfl_xor(p, off, 64);
  if (l == 0){
    float s = 1.0f/(1.0f + expf(-p));
    sc[row] = s;
    attout[row] = s;
  }
}

__global__ __launch_bounds__(1024) void k_pool(const float* __restrict__ emb, const float* __restrict__ sc,
     float* __restrict__ ep){
  int b = blockIdx.x; int f = threadIdx.x & 127; int ny = threadIdx.x >> 7;
  const float* e  = emb + ((size_t)(b<<10) + ny*128)*128 + f;
  const float* sb = sc + (b<<10) + ny*128;
  float s = 0.f;
  for (int n=0;n<128;n++) s += e[n*128]*sb[n];
  __shared__ float red[8][128];
  red[ny][f] = s;
  __syncthreads();
  if (ny == 0){
    float t = 0.f;
    #pragma unroll
    for (int i=0;i<8;i++) t += red[i][f];
    ep[b*128+f] = t;
  }
}

// ---------------- tensor network scoring ----------------
__global__ __launch_bounds__(256) void k_tnet(const float* __restrict__ e1, const float* __restrict__ e2,
    const float* __restrict__ tn_w, const float* __restrict__ tn_wb, const float* __restrict__ tn_bias,
    float* __restrict__ tsout){
  int b = blockIdx.x; int t = threadIdx.x; int tt = t & 15; int fs = t >> 4;
  __shared__ float E1[128], E2[128], red[16][17];
  if (t < 128){ E1[t] = e1[b*128+t]; E2[t] = e2[b*128+t]; }
  __syncthreads();
  float acc = 0.f;
  for (int f = fs*8; f < fs*8+8; f++){
    const float* tw = tn_w + f*128*16 + tt;
    float partial = 0.f;
    for (int g=0; g<128; g++) partial += E2[g]*tw[g*16];
    acc += E1[f]*partial;
  }
  red[fs][tt] = acc;
  __syncthreads();
  if (t < 16){
    float s = 0.f;
    #pragma unroll
    for (int i=0;i<16;i++) s += red[i][t];
    float acc2 = 0.f;
    for (int c=0;c<128;c++) acc2 += tn_wb[t*256+c]*E1[c] + tn_wb[t*256+128+c]*E2[c];
    float v = s + acc2 + tn_bias[t];
    tsout[b*16+t] = v > 0.f ? v : 0.f;
  }
}

__global__ __launch_bounds__(128) void k_score2(const float* __restrict__ ts,
   const float* __restrict__ fc1_w, const float* __restrict__ fc1_b,
   const float* __restrict__ sc_w, const float* __restrict__ sc_b, float* __restrict__ out){
  int t = threadIdx.x; int b = t >> 4, i = t & 15;
  __shared__ float h2[8][17];
  float a = 0.f;
  #pragma unroll
  for (int k=0;k<16;k++) a += ts[b*16+k]*fc1_w[i*16+k];
  a += fc1_b[i];
  h2[b][i] = a > 0.f ? a : 0.f;
  __syncthreads();
  if (t < 8){
    float s = 0.f;
    #pragma unroll
    for (int k=0;k<16;k++) s += h2[t][k]*sc_w[k];
    s += sc_b[0];
    out[t] = 1.0f/(1.0f + expf(-s));
  }
}

extern "C" void kernel_launch(void* const* d_in, const int* in_sizes, int n_in,
                              void* d_out, int out_size, void* d_ws, size_t ws_size,
                              hipStream_t stream){
  const float* f1  = (const float*)d_in[0];
  const float* f2  = (const float*)d_in[1];
  const float* sw1 = (const float*)d_in[2];  const float* sg1 = (const float*)d_in[3];  const float* sb1 = (const float*)d_in[4];
  const float* fw1 = (const float*)d_in[5];  const float* fg1 = (const float*)d_in[6];  const float* fb1 = (const float*)d_in[7];
  const float* sw2 = (const float*)d_in[8];  const float* sg2 = (const float*)d_in[9];  const float* sb2 = (const float*)d_in[10];
  const float* fw2 = (const float*)d_in[11]; const float* fg2 = (const float*)d_in[12]; const float* fb2 = (const float*)d_in[13];
  const float* sw3 = (const float*)d_in[14]; const float* sg3 = (const float*)d_in[15]; const float* sb3 = (const float*)d_in[16];
  const float* fw3 = (const float*)d_in[17]; const float* fg3 = (const float*)d_in[18]; const float* fb3 = (const float*)d_in[19];
  const float* ew  = (const float*)d_in[20]; const float* eg  = (const float*)d_in[21]; const float* eb  = (const float*)d_in[22];
  const float* att_w   = (const float*)d_in[23];
  const float* tn_w    = (const float*)d_in[24];
  const float* tn_wb   = (const float*)d_in[25];
  const float* tn_bias = (const float*)d_in[26];
  const float* fc1_w   = (const float*)d_in[27];
  const float* fc1_b   = (const float*)d_in[28];
  const float* sc_w    = (const float*)d_in[29];
  const float* sc_b    = (const float*)d_in[30];

  float* W    = (float*)d_ws;
  float* T0   = W;                  // 2,097,152  (16384 x <=128)
  float* T1   = W + 2097152;        // 2,097,152
  float* X3S3 = W + 4194304;        // 4,194,304  (16384 x 256)
  float* EMB  = W + 8388608;        // 2,097,152  (16384 x 128)
  float* XTb  = W + 10485760;       // 2,097,152  (<=128 x 16384)
  float* xx   = W + 12582912;       // 16384
  float* mb   = W + 12599296;       // 2048
  float* gcb  = W + 12601344;       // 2048
  float* scb  = W + 12603392;       // 16384
  float* ep   = W + 12619776;       // 2048
  float* tsb  = W + 12621824;       // 128
  int*   idxb = (int*)(W + 12621952); // 327680 ints
  float* REG  = W + 12949632;       // Y region (<= 4,194,304)

  (void)ws_size;
  float* out = (float*)d_out;

  auto edge = [&](const float* xin, int C, int O,
                  const float* w, const float* g, const float* bb,
                  float* xout, int ldo, int ooff, bool haveXT){
    k_xx<<<64, 256, 0, stream>>>(xin, xx, C);
    if (!haveXT)
      k_tr<<<dim3(C/64, 256), 256, 0, stream>>>(xin, XTb, C);
    k_dtopk4<<<4096, 64, 0, stream>>>(XTb, xin, xx, idxb, C);
    k_gthin<<<dim3(2*O/64, 512, 1), 256, 0, stream>>>(xin, w, REG, C, 2*O,
          O, nullptr, nullptr, 0);
    k_edge<<<16384, O, 0, stream>>>(REG, idxb, g, bb, xout, O, ldo, ooff);
  };

  // xyz path (both point clouds as batches 0-7 / 8-15); XT comes free from input layout
  k_extract<<<(8*3*1024+255)/256, 256, 0, stream>>>(f1, T0, 0, 3, 0);
  k_extract<<<(8*3*1024+255)/256, 256, 0, stream>>>(f2, T0, 0, 3, 8);
  k_extractT<<<(8*3*1024+255)/256, 256, 0, stream>>>(f1, XTb, 0, 3, 0);
  k_extractT<<<(8*3*1024+255)/256, 256, 0, stream>>>(f2, XTb, 0, 3, 8);
  edge(T0, 3,   64, sw1, sg1, sb1, T1, 64, 0, true);
  edge(T1, 64,  64, sw2, sg2, sb2, T0, 64, 0, false);
  edge(T0, 64, 128, sw3, sg3, sb3, X3S3, 256, 0, false);    // x3 -> cols 0..127
  // sem path
  k_extract<<<(8*128*1024+255)/256, 256, 0, stream>>>(f1, T0, 3, 128, 0);
  k_extract<<<(8*128*1024+255)/256, 256, 0, stream>>>(f2, T0, 3, 128, 8);
  k_extractT<<<(8*128*1024+255)/256, 256, 0, stream>>>(f1, XTb, 3, 128, 0);
  k_extractT<<<(8*128*1024+255)/256, 256, 0, stream>>>(f2, XTb, 3, 128, 8);
  edge(T0, 128, 64, fw1, fg1, fb1, T1, 64, 0, true);
  edge(T1, 64,  64, fw2, fg2, fb2, T0, 64, 0, false);
  edge(T0, 64, 128, fw3, fg3, fb3, X3S3, 256, 128, false);  // s3 -> cols 128..255
  // combine: emb = lrelu(eg * (X3S3 @ ew^T)/sqrt(1+eps) + eb)
  k_gthin<<<dim3(2, 512, 1), 256, 0, stream>>>(X3S3, ew, EMB, 256, 128,
        0, eg, eb, 1);
  // attention over all 16 batches
  k_mean<<<16, 1024, 0, stream>>>(EMB, mb);
  k_gc<<<16, 128, 0, stream>>>(mb, att_w, gcb);
  k_sc<<<16384, 64, 0, stream>>>(EMB, gcb, scb, out + 8);
  k_pool<<<16, 1024, 0, stream>>>(EMB, scb, ep);

  k_tnet<<<8, 256, 0, stream>>>(ep, ep + 1024, tn_w, tn_wb, tn_bias, tsb);
  k_score2<<<1, 128, 0, stream>>>(tsb, fc1_w, fc1_b, sc_w, sc_b, out);
}

// Round 14
// 786.127 us; speedup vs baseline: 2.0326x; 1.0525x over previous
//
#include <hip/hip_runtime.h>
#include <math.h>

#define INV_SQRT1P 0.99999500003749968754f   // 1/sqrt(1+1e-5)
#define REMOVED  -2.0e38f
#define NEGINIT  -3.0e38f

typedef short v8s  __attribute__((ext_vector_type(8)));
typedef float v16f __attribute__((ext_vector_type(16)));

static __device__ __forceinline__ float lrelu(float f){ return f >= 0.0f ? f : 0.2f*f; }

// ---------------- extract channels: feat (8,131,1024) -> rows [boff*1024..) (N,Cout) ----
__global__ void k_extract(const float* __restrict__ f, float* __restrict__ out, int c0, int Cout, int boff){
  int i = blockIdx.x*256 + threadIdx.x;
  int total = 8*Cout*1024;
  if (i >= total) return;
  int n  = i & 1023;
  int bc = i >> 10;
  int c  = bc % Cout;
  int b  = bc / Cout;
  out[((size_t)(((b+boff)<<10)+n))*Cout + c] = f[((size_t)(b*131 + c0 + c) << 10) + n];
}

// ---------------- row sum of squares: x (16384,C) -> xx (16384) ----------------
__global__ void k_xx(const float* __restrict__ x, float* __restrict__ xx, int C){
  int r = blockIdx.x*256 + threadIdx.x;
  if (r >= 16384) return;
  const float* xr = x + (size_t)r*C;
  float s = 0.f;
  for (int c=0;c<C;c++) s += xr[c]*xr[c];
  xx[r] = s;
}

// ---------------- fp32 -> (hi,lo) bf16 split, zero-padded to Kp ----------------
__global__ void k_split(const float* __restrict__ X, unsigned short* __restrict__ XH,
                        unsigned short* __restrict__ XL, int C, int Kp){
  int i = blockIdx.x*256 + threadIdx.x;
  if (i >= 16384*Kp) return;
  int r = i / Kp, k = i - r*Kp;
  float x = (k < C) ? X[(size_t)r*C + k] : 0.f;
  unsigned u = __float_as_uint(x);
  unsigned h16 = (u + 0x7fffu + ((u>>16)&1u)) >> 16;
  float hf = __uint_as_float(h16 << 16);
  float lo = x - hf;
  unsigned ul = __float_as_uint(lo);
  unsigned l16 = (ul + 0x7fffu + ((ul>>16)&1u)) >> 16;
  XH[i] = (unsigned short)h16;
  XL[i] = (unsigned short)l16;
}

// ---------------- S = neg_d via bf16x3-split MFMA: 1 wave per 32x32 tile --------------
// S ~= Ahi.Bhi + Ahi.Blo + Alo.Bhi (lo.lo dropped, ~2^-18 relative).
// A/B frags load identically from row-major bf16 (X.X^T): lane row base+(l&31),
// k = (l>>5)*8 + j. C/D layout (m74/m101): col=lane&31, row=(reg&3)+8*(reg>>2)+4*(lane>>5).
__global__ __launch_bounds__(256) void k_gsmf(const unsigned short* __restrict__ XH,
    const unsigned short* __restrict__ XL, float* __restrict__ S,
    const float* __restrict__ xx, int Kp){
  int w = threadIdx.x >> 6;
  int l = threadIdx.x & 63;
  int tile  = blockIdx.x*4 + w;        // 0..1023
  int batch = blockIdx.y;              // 0..15
  int tm = tile >> 5, tn = tile & 31;
  int rbase = tm*32, cbase = tn*32;
  int mrow = l & 31;
  int koff = (l >> 5) << 3;
  size_t arow = (size_t)((batch<<10) + rbase + mrow)*Kp + koff;
  size_t brow = (size_t)((batch<<10) + cbase + mrow)*Kp + koff;
  v16f acc;
  #pragma unroll
  for (int i=0;i<16;i++) acc[i] = 0.f;
  for (int k0=0; k0<Kp; k0+=16){
    v8s Ah = *(const v8s*)(XH + arow + k0);
    v8s Al = *(const v8s*)(XL + arow + k0);
    v8s Bh = *(const v8s*)(XH + brow + k0);
    v8s Bl = *(const v8s*)(XL + brow + k0);
    acc = __builtin_amdgcn_mfma_f32_32x32x16_bf16(Ah, Bh, acc, 0, 0, 0);
    acc = __builtin_amdgcn_mfma_f32_32x32x16_bf16(Ah, Bl, acc, 0, 0, 0);
    acc = __builtin_amdgcn_mfma_f32_32x32x16_bf16(Al, Bh, acc, 0, 0, 0);
  }
  const float* xxb = xx + (batch<<10);
  float xc = xxb[cbase + (l & 31)];
  float* Sb = S + (size_t)batch*1048576;
  #pragma unroll
  for (int r=0;r<16;r++){
    int rl_ = (r&3) + ((r>>2)<<3) + ((l>>5)<<2);
    float o = 2.f*acc[r] - xxb[rbase + rl_] - xc;
    Sb[(size_t)(rbase + rl_)*1024 + cbase + (l&31)] = o;
  }
}

// ---------------- thin NT GEMM: 32 rows x 64 cols per block, 2x4/thread ----------------
__global__ __launch_bounds__(256) void k_gthin(
    const float* __restrict__ Am, const float* __restrict__ Bm, float* __restrict__ Om,
    int K, int ldo, int wmode, const float* __restrict__ p1, const float* __restrict__ p2, int ep)
{
  __shared__ float As[64][33];
  __shared__ float Bs[64][68];
  int tid = threadIdx.x;
  int tx = tid & 15, ty = tid >> 4;
  int rbase = blockIdx.y*32, cbase = blockIdx.x*64;
  float acc[2][4];
  #pragma unroll
  for (int i=0;i<2;i++){ acc[i][0]=0.f; acc[i][1]=0.f; acc[i][2]=0.f; acc[i][3]=0.f; }

  for (int c0=0; c0<K; c0+=64){
    int cw = K - c0; if (cw > 64) cw = 64;
    #pragma unroll
    for (int p=0; p<2; p++){
      int idx = p*256 + tid;
      int kq = idx & 15, row = idx >> 4;
      const float* src = Am + (size_t)(rbase+row)*K + c0 + kq*4;
      float4 v = {0.f,0.f,0.f,0.f};
      if (kq*4 + 4 <= cw) v = *(const float4*)src;
      else {
        if (kq*4+0 < cw) v.x = src[0];
        if (kq*4+1 < cw) v.y = src[1];
        if (kq*4+2 < cw) v.z = src[2];
        if (kq*4+3 < cw) v.w = src[3];
      }
      As[kq*4+0][row]=v.x; As[kq*4+1][row]=v.y; As[kq*4+2][row]=v.z; As[kq*4+3][row]=v.w;
    }
    #pragma unroll
    for (int p=0; p<4; p++){
      int idx = p*256 + tid;
      int kq = idx & 15, col = idx >> 4;
      int j = cbase + col;
      const float* src = (wmode > 0)
          ? ((j < wmode) ? Bm + (size_t)j*2*K + c0 + kq*4
                         : Bm + (size_t)(j-wmode)*2*K + K + c0 + kq*4)
          : Bm + (size_t)j*K + c0 + kq*4;
      float4 v = {0.f,0.f,0.f,0.f};
      if (kq*4 + 4 <= cw) v = *(const float4*)src;
      else {
        if (kq*4+0 < cw) v.x = src[0];
        if (kq*4+1 < cw) v.y = src[1];
        if (kq*4+2 < cw) v.z = src[2];
        if (kq*4+3 < cw) v.w = src[3];
      }
      int swb = (kq & 14) << 1;
      int cs = col ^ swb;
      Bs[kq*4+0][cs]=v.x; Bs[kq*4+1][cs]=v.y; Bs[kq*4+2][cs]=v.z; Bs[kq*4+3][cs]=v.w;
    }
    __syncthreads();
    for (int k=0;k<cw;k++){
      int sw = ((k>>3)&7)<<2;
      float a0 = As[k][ty*2], a1 = As[k][ty*2+1];
      float b[4];
      *(float4*)b = *(const float4*)&Bs[k][(tx*4) ^ sw];
      acc[0][0]+=a0*b[0]; acc[0][1]+=a0*b[1]; acc[0][2]+=a0*b[2]; acc[0][3]+=a0*b[3];
      acc[1][0]+=a1*b[0]; acc[1][1]+=a1*b[1]; acc[1][2]+=a1*b[2]; acc[1][3]+=a1*b[3];
    }
    __syncthreads();
  }
  #pragma unroll
  for (int i=0;i<2;i++){
    int r = rbase + ty*2 + i;
    float o[4];
    #pragma unroll
    for (int j=0;j<4;j++){
      int cc = cbase + tx*4 + j;
      float v = acc[i][j];
      if (ep == 1) v = lrelu(p1[cc]*v*INV_SQRT1P + p2[cc]);
      o[j] = v;
    }
    *(float4*)(Om + (size_t)r*ldo + cbase + tx*4) = *(float4*)o;
  }
}

// ---------------- top-20 of a 1024-length neg_d row (1 wave per row) ----------------
__global__ __launch_bounds__(64) void k_topk(const float* __restrict__ S,
      int* __restrict__ idx, int b0){
  int rl = blockIdx.x;
  int bz = rl >> 10; int n = rl & 1023;
  int b  = b0 + bz;
  int l  = threadIdx.x;
  const float4* Srow = (const float4*)(S + (size_t)rl*1024);
  float4 q[4];
  #pragma unroll
  for (int j=0;j<4;j++) q[j] = Srow[l + 64*j];
  int out_base = (((b<<10)+n))*20;

  float lmax = fmaxf(fmaxf(fmaxf(q[0].x,q[0].y),fmaxf(q[0].z,q[0].w)),
               fmaxf(fmaxf(fmaxf(q[1].x,q[1].y),fmaxf(q[1].z,q[1].w)),
               fmaxf(fmaxf(fmaxf(q[2].x,q[2].y),fmaxf(q[2].z,q[2].w)),
                     fmaxf(fmaxf(q[3].x,q[3].y),fmaxf(q[3].z,q[3].w)))));

  float sv = lmax;
  #pragma unroll
  for (int k=2; k<=64; k<<=1){
    #pragma unroll
    for (int j=k>>1; j>0; j>>=1){
      float o = __shfl_xor(sv, j, 64);
      bool a  = (l & k) == 0;
      bool bb = (l & j) == 0;
      sv = (a == bb) ? fminf(sv, o) : fmaxf(sv, o);
    }
  }
  float tau = __shfl(sv, 44, 64);

  float vv[16] = {q[0].x,q[0].y,q[0].z,q[0].w, q[1].x,q[1].y,q[1].z,q[1].w,
                  q[2].x,q[2].y,q[2].z,q[2].w, q[3].x,q[3].y,q[3].z,q[3].w};
  int cnt = 0;
  #pragma unroll
  for (int j=0;j<16;j++) cnt += (vv[j] >= tau) ? 1 : 0;
  int inc = cnt;
  #pragma unroll
  for (int off=1; off<64; off<<=1){
    int t = __shfl_up(inc, off, 64);
    inc += (l >= off) ? t : 0;
  }
  int Ns = __shfl(inc, 63, 64);

  __shared__ unsigned long long sl[128];

  if (Ns <= 128){
    sl[l] = 0ull; sl[64+l] = 0ull;
    __syncthreads();
    int slot = inc - cnt;
    #pragma unroll
    for (int j=0;j<16;j++){
      if (vv[j] >= tau){
        int m = 4*l + 64*(j & ~3) + (j & 3);
        unsigned int mv = __float_as_uint(vv[j]);
        mv = (mv & 0x80000000u) ? ~mv : (mv | 0x80000000u);
        sl[slot] = ((unsigned long long)mv << 10) | (unsigned)(1023 - m);
        slot++;
      }
    }
    __syncthreads();
    if (Ns <= 64){
      unsigned long long key = sl[l];
      #pragma unroll
      for (int k=2; k<=64; k<<=1){
        #pragma unroll
        for (int j=k>>1; j>0; j>>=1){
          unsigned long long o = __shfl_xor(key, j, 64);
          bool a  = (l & k) == 0;
          bool bb = (l & j) == 0;
          unsigned long long mx = key > o ? key : o;
          unsigned long long mn = key > o ? o : key;
          key = (a == bb) ? mx : mn;
        }
      }
      if (l < 20) idx[out_base + l] = 1023 - (int)(key & 1023ull);
    } else {
      unsigned long long c0 = sl[l], c1 = sl[64+l];
      for (int kk=0; kk<20; kk++){
        unsigned long long m = c0 > c1 ? c0 : c1;
        #pragma unroll
        for (int off=32; off>0; off>>=1){
          unsigned long long o = __shfl_xor(m, off, 64);
          m = o > m ? o : m;
        }
        c0 = (c0 == m) ? 0ull : c0;
        c1 = (c1 == m) ? 0ull : c1;
        if (l == 0) idx[out_base + kk] = 1023 - (int)(m & 1023ull);
      }
    }
  } else {
    for (int kk=0; kk<20; kk++){
      float bv = NEGINIT; int bi = 0x3fffffff;
      #pragma unroll
      for (int j=0;j<16;j++){
        int m = 4*l + 64*(j & ~3) + (j & 3);
        if (vv[j] > bv || (vv[j] == bv && m < bi)){ bv = vv[j]; bi = m; }
      }
      #pragma unroll
      for (int off=32; off>0; off>>=1){
        float ov = __shfl_xor(bv, off, 64);
        int   oi = __shfl_xor(bi, off, 64);
        if (ov > bv || (ov == bv && oi < bi)){ bv = ov; bi = oi; }
      }
      #pragma unroll
      for (int j=0;j<16;j++){
        int m = 4*l + 64*(j & ~3) + (j & 3);
        vv[j] = (m == bi) ? REMOVED : vv[j];
      }
      if (l == 0) idx[out_base + kk] = bi;
    }
  }
}

// ---------------- edge epilogue: gather Y1 at neighbors, +center, scale/bias/lrelu, max_k
__global__ void k_edge(const float* __restrict__ Y, const int* __restrict__ idx,
    const float* __restrict__ g, const float* __restrict__ bias,
    float* __restrict__ out, int O, int ldo, int ooff){
  int row = blockIdx.x; int o = threadIdx.x; int b = row >> 10;
  __shared__ int js[20];
  if (threadIdx.x < 20) js[threadIdx.x] = idx[row*20 + threadIdx.x];
  __syncthreads();
  int O2 = O*2;
  float y1c = Y[(size_t)row*O2 + o];
  float d   = Y[(size_t)row*O2 + O + o] - y1c;
  float sc  = g[o] * INV_SQRT1P;
  float bb  = bias[o];
  const float* Yb = Y + ((size_t)(b<<10))*O2;
  float best = -1e38f;
  #pragma unroll
  for (int k=0;k<20;k++){
    float f = sc * (Yb[(size_t)js[k]*O2 + o] + d) + bb;
    best = fmaxf(best, lrelu(f));
  }
  out[(size_t)row*ldo + ooff + o] = best;
}

// ---------------- attention (16 batches) ----------------
__global__ __launch_bounds__(1024) void k_mean(const float* __restrict__ emb, float* __restrict__ m){
  int b = blockIdx.x; int f = threadIdx.x & 127; int ny = threadIdx.x >> 7;
  const float* e = emb + ((size_t)(b<<10) + ny*128)*128 + f;
  float s = 0.f;
  for (int n=0;n<128;n++) s += e[n*128];
  __shared__ float red[8][128];
  red[ny][f] = s;
  __syncthreads();
  if (ny == 0){
    float t = 0.f;
    #pragma unroll
    for (int i=0;i<8;i++) t += red[i][f];
    m[b*128+f] = t * (1.0f/1024.0f);
  }
}

__global__ __launch_bounds__(128) void k_gc(const float* __restrict__ m, const float* __restrict__ att_w,
     float* __restrict__ gc){
  int b = blockIdx.x, g = threadIdx.x;
  __shared__ float mr[128];
  mr[g] = m[b*128+g];
  __syncthreads();
  float s = 0.f;
  for (int f=0; f<128; f++) s += mr[f]*att_w[f*128+g];
  gc[b*128+g] = tanhf(s);
}

__global__ __launch_bounds__(64) void k_sc(const float* __restrict__ emb, const float* __restrict__ gc,
     float* __restrict__ sc, float* __restrict__ attout){
  int row = blockIdx.x; int l = threadIdx.x; int b = row >> 10;
  const float* e  = emb + (size_t)row*128;
  const float* gb = gc + b*128;
  float p = e[l]*gb[l] + e[l+64]*gb[l+64];
  #pragma unroll
  for (int off=32; off>0; off>>=1) p += __shfl_xor(p, off, 64);
  if (l == 0){
    float s = 1.0f/(1.0f + expf(-p));
    sc[row] = s;
    attout[row] = s;
  }
}

__global__ __launch_bounds__(1024) void k_pool(const float* __restrict__ emb, const float* __restrict__ sc,
     float* __restrict__ ep){
  int b = blockIdx.x; int f = threadIdx.x & 127; int ny = threadIdx.x >> 7;
  const float* e  = emb + ((size_t)(b<<10) + ny*128)*128 + f;
  const float* sb = sc + (b<<10) + ny*128;
  float s = 0.f;
  for (int n=0;n<128;n++) s += e[n*128]*sb[n];
  __shared__ float red[8][128];
  red[ny][f] = s;
  __syncthreads();
  if (ny == 0){
    float t = 0.f;
    #pragma unroll
    for (int i=0;i<8;i++) t += red[i][f];
    ep[b*128+f] = t;
  }
}

// ---------------- tensor network scoring ----------------
__global__ __launch_bounds__(256) void k_tnet(const float* __restrict__ e1, const float* __restrict__ e2,
    const float* __restrict__ tn_w, const float* __restrict__ tn_wb, const float* __restrict__ tn_bias,
    float* __restrict__ tsout){
  int b = blockIdx.x; int t = threadIdx.x; int tt = t & 15; int fs = t >> 4;
  __shared__ float E1[128], E2[128], red[16][17];
  if (t < 128){ E1[t] = e1[b*128+t]; E2[t] = e2[b*128+t]; }
  __syncthreads();
  float acc = 0.f;
  for (int f = fs*8; f < fs*8+8; f++){
    const float* tw = tn_w + f*128*16 + tt;
    float partial = 0.f;
    for (int g=0; g<128; g++) partial += E2[g]*tw[g*16];
    acc += E1[f]*partial;
  }
  red[fs][tt] = acc;
  __syncthreads();
  if (t < 16){
    float s = 0.f;
    #pragma unroll
    for (int i=0;i<16;i++) s += red[i][t];
    float acc2 = 0.f;
    for (int c=0;c<128;c++) acc2 += tn_wb[t*256+c]*E1[c] + tn_wb[t*256+128+c]*E2[c];
    float v = s + acc2 + tn_bias[t];
    tsout[b*16+t] = v > 0.f ? v : 0.f;
  }
}

__global__ __launch_bounds__(128) void k_score2(const float* __restrict__ ts,
   const float* __restrict__ fc1_w, const float* __restrict__ fc1_b,
   const float* __restrict__ sc_w, const float* __restrict__ sc_b, float* __restrict__ out){
  int t = threadIdx.x; int b = t >> 4, i = t & 15;
  __shared__ float h2[8][17];
  float a = 0.f;
  #pragma unroll
  for (int k=0;k<16;k++) a += ts[b*16+k]*fc1_w[i*16+k];
  a += fc1_b[i];
  h2[b][i] = a > 0.f ? a : 0.f;
  __syncthreads();
  if (t < 8){
    float s = 0.f;
    #pragma unroll
    for (int k=0;k<16;k++) s += h2[t][k]*sc_w[k];
    s += sc_b[0];
    out[t] = 1.0f/(1.0f + expf(-s));
  }
}

extern "C" void kernel_launch(void* const* d_in, const int* in_sizes, int n_in,
                              void* d_out, int out_size, void* d_ws, size_t ws_size,
                              hipStream_t stream){
  const float* f1  = (const float*)d_in[0];
  const float* f2  = (const float*)d_in[1];
  const float* sw1 = (const float*)d_in[2];  const float* sg1 = (const float*)d_in[3];  const float* sb1 = (const float*)d_in[4];
  const float* fw1 = (const float*)d_in[5];  const float* fg1 = (const float*)d_in[6];  const float* fb1 = (const float*)d_in[7];
  const float* sw2 = (const float*)d_in[8];  const float* sg2 = (const float*)d_in[9];  const float* sb2 = (const float*)d_in[10];
  const float* fw2 = (const float*)d_in[11]; const float* fg2 = (const float*)d_in[12]; const float* fb2 = (const float*)d_in[13];
  const float* sw3 = (const float*)d_in[14]; const float* sg3 = (const float*)d_in[15]; const float* sb3 = (const float*)d_in[16];
  const float* fw3 = (const float*)d_in[17]; const float* fg3 = (const float*)d_in[18]; const float* fb3 = (const float*)d_in[19];
  const float* ew  = (const float*)d_in[20]; const float* eg  = (const float*)d_in[21]; const float* eb  = (const float*)d_in[22];
  const float* att_w   = (const float*)d_in[23];
  const float* tn_w    = (const float*)d_in[24];
  const float* tn_wb   = (const float*)d_in[25];
  const float* tn_bias = (const float*)d_in[26];
  const float* fc1_w   = (const float*)d_in[27];
  const float* fc1_b   = (const float*)d_in[28];
  const float* sc_w    = (const float*)d_in[29];
  const float* sc_b    = (const float*)d_in[30];

  float* W    = (float*)d_ws;
  float* T0   = W;                  // 2,097,152  (16384 x <=128)
  float* T1   = W + 2097152;        // 2,097,152
  float* X3S3 = W + 4194304;        // 4,194,304  (16384 x 256)
  float* EMB  = W + 8388608;        // 2,097,152  (16384 x 128)
  float* xx   = W + 10485760;       // 16384
  float* mb   = W + 10502144;       // 2048
  float* gcb  = W + 10504192;       // 2048
  float* scb  = W + 10506240;       // 16384
  float* ep   = W + 10522624;       // 2048
  float* tsb  = W + 10524672;       // 128
  int*   idxb = (int*)(W + 10524800);            // 327680 ints
  unsigned short* XH = (unsigned short*)(W + 10852480); // 16384x128 bf16 (1M floats)
  unsigned short* XL = (unsigned short*)(W + 11901056); // 16384x128 bf16 (1M floats)
  float* REG  = W + 12949632;       // S: 16 x 1,048,576 = 16M floats; Y reuses (<=4M)

  (void)ws_size;
  float* out = (float*)d_out;

  auto edge = [&](const float* xin, int C, int O,
                  const float* w, const float* g, const float* bb,
                  float* xout, int ldo, int ooff){
    int Kp = (C + 15) & ~15;
    k_xx<<<64, 256, 0, stream>>>(xin, xx, C);
    k_split<<<(16384*Kp+255)/256, 256, 0, stream>>>(xin, XH, XL, C, Kp);
    k_gsmf<<<dim3(256, 16), 256, 0, stream>>>(XH, XL, REG, xx, Kp);
    k_topk<<<16384, 64, 0, stream>>>(REG, idxb, 0);
    // Y reuses REG (stream order: topk consumed S already)
    k_gthin<<<dim3(2*O/64, 512, 1), 256, 0, stream>>>(xin, w, REG, C, 2*O,
          O, nullptr, nullptr, 0);
    k_edge<<<16384, O, 0, stream>>>(REG, idxb, g, bb, xout, O, ldo, ooff);
  };

  // xyz path (both point clouds as batches 0-7 / 8-15)
  k_extract<<<(8*3*1024+255)/256, 256, 0, stream>>>(f1, T0, 0, 3, 0);
  k_extract<<<(8*3*1024+255)/256, 256, 0, stream>>>(f2, T0, 0, 3, 8);
  edge(T0, 3,   64, sw1, sg1, sb1, T1, 64, 0);
  edge(T1, 64,  64, sw2, sg2, sb2, T0, 64, 0);
  edge(T0, 64, 128, sw3, sg3, sb3, X3S3, 256, 0);    // x3 -> cols 0..127
  // sem path
  k_extract<<<(8*128*1024+255)/256, 256, 0, stream>>>(f1, T0, 3, 128, 0);
  k_extract<<<(8*128*1024+255)/256, 256, 0, stream>>>(f2, T0, 3, 128, 8);
  edge(T0, 128, 64, fw1, fg1, fb1, T1, 64, 0);
  edge(T1, 64,  64, fw2, fg2, fb2, T0, 64, 0);
  edge(T0, 64, 128, fw3, fg3, fb3, X3S3, 256, 128);  // s3 -> cols 128..255
  // combine: emb = lrelu(eg * (X3S3 @ ew^T)/sqrt(1+eps) + eb)
  k_gthin<<<dim3(2, 512, 1), 256, 0, stream>>>(X3S3, ew, EMB, 256, 128,
        0, eg, eb, 1);
  // attention over all 16 batches
  k_mean<<<16, 1024, 0, stream>>>(EMB, mb);
  k_gc<<<16, 128, 0, stream>>>(mb, att_w, gcb);
  k_sc<<<16384, 64, 0, stream>>>(EMB, gcb, scb, out + 8);
  k_pool<<<16, 1024, 0, stream>>>(EMB, scb, ep);

  k_tnet<<<8, 256, 0, stream>>>(ep, ep + 1024, tn_w, tn_wb, tn_bias, tsb);
  k_score2<<<1, 128, 0, stream>>>(tsb, fc1_w, fc1_b, sc_w, sc_b, out);
}

// Round 15
// 676.822 us; speedup vs baseline: 2.3609x; 1.1615x over previous
//
#include <hip/hip_runtime.h>
#include <math.h>

#define INV_SQRT1P 0.99999500003749968754f   // 1/sqrt(1+1e-5)
#define REMOVED  -2.0e38f
#define NEGINIT  -3.0e38f

typedef short v8s  __attribute__((ext_vector_type(8)));
typedef float v16f __attribute__((ext_vector_type(16)));

static __device__ __forceinline__ float lrelu(float f){ return f >= 0.0f ? f : 0.2f*f; }

// ---------------- extract channels: feat (8,131,1024) -> rows [boff*1024..) (N,Cout) ----
__global__ void k_extract(const float* __restrict__ f, float* __restrict__ out, int c0, int Cout, int boff){
  int i = blockIdx.x*256 + threadIdx.x;
  int total = 8*Cout*1024;
  if (i >= total) return;
  int n  = i & 1023;
  int bc = i >> 10;
  int c  = bc % Cout;
  int b  = bc / Cout;
  out[((size_t)(((b+boff)<<10)+n))*Cout + c] = f[((size_t)(b*131 + c0 + c) << 10) + n];
}

// ---------------- row sum of squares: x (16384,C) -> xx (16384) ----------------
__global__ void k_xx(const float* __restrict__ x, float* __restrict__ xx, int C){
  int r = blockIdx.x*256 + threadIdx.x;
  if (r >= 16384) return;
  const float* xr = x + (size_t)r*C;
  float s = 0.f;
  for (int c=0;c<C;c++) s += xr[c]*xr[c];
  xx[r] = s;
}

// ---------------- pack fp32 X into MFMA-fragment-major bf16 hi/lo ----------------
// Chunk c = rowblock*(Kp/16)+kc holds a 32x16 tile as [lane][8]: lane l, elem j =
// X[rb*32+(l&31)][kc*16+(l>>5)*8+j]. Wave then loads a fragment as ONE coalesced b128.
__global__ void k_pack(const float* __restrict__ X, unsigned short* __restrict__ PH,
                       unsigned short* __restrict__ PL, int C, int Kp){
  int gid = blockIdx.x*256 + threadIdx.x;
  int nkc = Kp >> 4;
  if (gid >= 512*nkc*64) return;
  int lane = gid & 63;
  int chunk = gid >> 6;
  int rb = chunk / nkc, kc = chunk - rb*nkc;
  int row = rb*32 + (lane & 31);
  int k0 = kc*16 + ((lane>>5)<<3);
  unsigned short h[8], lo[8];
  const float* Xr = X + (size_t)row*C;
  #pragma unroll
  for (int j=0;j<8;j++){
    int k = k0 + j;
    float x = (k < C) ? Xr[k] : 0.f;
    unsigned u = __float_as_uint(x);
    unsigned h16 = (u + 0x7fffu + ((u>>16)&1u)) >> 16;
    float hf = __uint_as_float(h16 << 16);
    float lf = x - hf;
    unsigned ul = __float_as_uint(lf);
    unsigned l16 = (ul + 0x7fffu + ((ul>>16)&1u)) >> 16;
    h[j] = (unsigned short)h16; lo[j] = (unsigned short)l16;
  }
  size_t o = (size_t)chunk*512 + lane*8;
  *(v8s*)(PH + o) = *(v8s*)h;
  *(v8s*)(PL + o) = *(v8s*)lo;
}

// ---------------- S = neg_d via bf16x3-split MFMA, packed fragments --------------
// Wave computes 32 rows x 64 cols (2 tiles); 6 coalesced b128 loads -> 6 MFMAs per
// K16-step, acc chains interleaved. C/D layout (m74/m101):
// col=lane&31, row=(reg&3)+8*(reg>>2)+4*(lane>>5).
__global__ __launch_bounds__(256) void k_gsmf(const unsigned short* __restrict__ PH,
    const unsigned short* __restrict__ PL, float* __restrict__ S,
    const float* __restrict__ xx, int Kp){
  int w = threadIdx.x >> 6;
  int l = threadIdx.x & 63;
  int gw = blockIdx.x*4 + w;           // 0..8191
  int batch = gw >> 9;                 // /512
  int t = gw & 511;
  int tm = t >> 4, tp = t & 15;        // row tile 32, col pair (64 cols)
  int nkc = Kp >> 4;
  int rbm = batch*32 + tm;
  int cb0 = batch*32 + 2*tp, cb1 = cb0 + 1;
  size_t ao  = ((size_t)rbm*nkc)*512 + l*8;
  size_t b0o = ((size_t)cb0*nkc)*512 + l*8;
  size_t b1o = ((size_t)cb1*nkc)*512 + l*8;
  v16f acc0, acc1;
  #pragma unroll
  for (int i=0;i<16;i++){ acc0[i] = 0.f; acc1[i] = 0.f; }
  for (int kc=0; kc<nkc; kc++){
    v8s Ah  = *(const v8s*)(PH + ao);
    v8s Al  = *(const v8s*)(PL + ao);
    v8s B0h = *(const v8s*)(PH + b0o);
    v8s B0l = *(const v8s*)(PL + b0o);
    v8s B1h = *(const v8s*)(PH + b1o);
    v8s B1l = *(const v8s*)(PL + b1o);
    acc0 = __builtin_amdgcn_mfma_f32_32x32x16_bf16(Ah, B0h, acc0, 0, 0, 0);
    acc1 = __builtin_amdgcn_mfma_f32_32x32x16_bf16(Ah, B1h, acc1, 0, 0, 0);
    acc0 = __builtin_amdgcn_mfma_f32_32x32x16_bf16(Ah, B0l, acc0, 0, 0, 0);
    acc1 = __builtin_amdgcn_mfma_f32_32x32x16_bf16(Ah, B1l, acc1, 0, 0, 0);
    acc0 = __builtin_amdgcn_mfma_f32_32x32x16_bf16(Al, B0h, acc0, 0, 0, 0);
    acc1 = __builtin_amdgcn_mfma_f32_32x32x16_bf16(Al, B1h, acc1, 0, 0, 0);
    ao += 512; b0o += 512; b1o += 512;
  }
  const float* xxb = xx + (batch<<10);
  int rbase = tm*32, cbase0 = tp*64, cbase1 = tp*64 + 32;
  float xc0 = xxb[cbase0 + (l & 31)];
  float xc1 = xxb[cbase1 + (l & 31)];
  float* Sb = S + (size_t)batch*1048576;
  #pragma unroll
  for (int r=0;r<16;r++){
    int rl_ = (r&3) + ((r>>2)<<3) + ((l>>5)<<2);
    float xr = xxb[rbase + rl_];
    Sb[(size_t)(rbase + rl_)*1024 + cbase0 + (l&31)] = 2.f*acc0[r] - xr - xc0;
    Sb[(size_t)(rbase + rl_)*1024 + cbase1 + (l&31)] = 2.f*acc1[r] - xr - xc1;
  }
}

// ---------------- thin NT GEMM: 32 rows x 64 cols per block, 2x4/thread ----------------
__global__ __launch_bounds__(256) void k_gthin(
    const float* __restrict__ Am, const float* __restrict__ Bm, float* __restrict__ Om,
    int K, int ldo, int wmode, const float* __restrict__ p1, const float* __restrict__ p2, int ep)
{
  __shared__ float As[64][33];
  __shared__ float Bs[64][68];
  int tid = threadIdx.x;
  int tx = tid & 15, ty = tid >> 4;
  int rbase = blockIdx.y*32, cbase = blockIdx.x*64;
  float acc[2][4];
  #pragma unroll
  for (int i=0;i<2;i++){ acc[i][0]=0.f; acc[i][1]=0.f; acc[i][2]=0.f; acc[i][3]=0.f; }

  for (int c0=0; c0<K; c0+=64){
    int cw = K - c0; if (cw > 64) cw = 64;
    #pragma unroll
    for (int p=0; p<2; p++){
      int idx = p*256 + tid;
      int kq = idx & 15, row = idx >> 4;
      const float* src = Am + (size_t)(rbase+row)*K + c0 + kq*4;
      float4 v = {0.f,0.f,0.f,0.f};
      if (kq*4 + 4 <= cw) v = *(const float4*)src;
      else {
        if (kq*4+0 < cw) v.x = src[0];
        if (kq*4+1 < cw) v.y = src[1];
        if (kq*4+2 < cw) v.z = src[2];
        if (kq*4+3 < cw) v.w = src[3];
      }
      As[kq*4+0][row]=v.x; As[kq*4+1][row]=v.y; As[kq*4+2][row]=v.z; As[kq*4+3][row]=v.w;
    }
    #pragma unroll
    for (int p=0; p<4; p++){
      int idx = p*256 + tid;
      int kq = idx & 15, col = idx >> 4;
      int j = cbase + col;
      const float* src = (wmode > 0)
          ? ((j < wmode) ? Bm + (size_t)j*2*K + c0 + kq*4
                         : Bm + (size_t)(j-wmode)*2*K + K + c0 + kq*4)
          : Bm + (size_t)j*K + c0 + kq*4;
      float4 v = {0.f,0.f,0.f,0.f};
      if (kq*4 + 4 <= cw) v = *(const float4*)src;
      else {
        if (kq*4+0 < cw) v.x = src[0];
        if (kq*4+1 < cw) v.y = src[1];
        if (kq*4+2 < cw) v.z = src[2];
        if (kq*4+3 < cw) v.w = src[3];
      }
      int swb = (kq & 14) << 1;
      int cs = col ^ swb;
      Bs[kq*4+0][cs]=v.x; Bs[kq*4+1][cs]=v.y; Bs[kq*4+2][cs]=v.z; Bs[kq*4+3][cs]=v.w;
    }
    __syncthreads();
    for (int k=0;k<cw;k++){
      int sw = ((k>>3)&7)<<2;
      float a0 = As[k][ty*2], a1 = As[k][ty*2+1];
      float b[4];
      *(float4*)b = *(const float4*)&Bs[k][(tx*4) ^ sw];
      acc[0][0]+=a0*b[0]; acc[0][1]+=a0*b[1]; acc[0][2]+=a0*b[2]; acc[0][3]+=a0*b[3];
      acc[1][0]+=a1*b[0]; acc[1][1]+=a1*b[1]; acc[1][2]+=a1*b[2]; acc[1][3]+=a1*b[3];
    }
    __syncthreads();
  }
  #pragma unroll
  for (int i=0;i<2;i++){
    int r = rbase + ty*2 + i;
    float o[4];
    #pragma unroll
    for (int j=0;j<4;j++){
      int cc = cbase + tx*4 + j;
      float v = acc[i][j];
      if (ep == 1) v = lrelu(p1[cc]*v*INV_SQRT1P + p2[cc]);
      o[j] = v;
    }
    *(float4*)(Om + (size_t)r*ldo + cbase + tx*4) = *(float4*)o;
  }
}

// ---------------- top-20 of a 1024-length neg_d row (1 wave per row) ----------------
__global__ __launch_bounds__(64) void k_topk(const float* __restrict__ S,
      int* __restrict__ idx, int b0){
  int rl = blockIdx.x;
  int bz = rl >> 10; int n = rl & 1023;
  int b  = b0 + bz;
  int l  = threadIdx.x;
  const float4* Srow = (const float4*)(S + (size_t)rl*1024);
  float4 q[4];
  #pragma unroll
  for (int j=0;j<4;j++) q[j] = Srow[l + 64*j];
  int out_base = (((b<<10)+n))*20;

  float lmax = fmaxf(fmaxf(fmaxf(q[0].x,q[0].y),fmaxf(q[0].z,q[0].w)),
               fmaxf(fmaxf(fmaxf(q[1].x,q[1].y),fmaxf(q[1].z,q[1].w)),
               fmaxf(fmaxf(fmaxf(q[2].x,q[2].y),fmaxf(q[2].z,q[2].w)),
                     fmaxf(fmaxf(q[3].x,q[3].y),fmaxf(q[3].z,q[3].w)))));

  float sv = lmax;
  #pragma unroll
  for (int k=2; k<=64; k<<=1){
    #pragma unroll
    for (int j=k>>1; j>0; j>>=1){
      float o = __shfl_xor(sv, j, 64);
      bool a  = (l & k) == 0;
      bool bb = (l & j) == 0;
      sv = (a == bb) ? fminf(sv, o) : fmaxf(sv, o);
    }
  }
  float tau = __shfl(sv, 44, 64);

  float vv[16] = {q[0].x,q[0].y,q[0].z,q[0].w, q[1].x,q[1].y,q[1].z,q[1].w,
                  q[2].x,q[2].y,q[2].z,q[2].w, q[3].x,q[3].y,q[3].z,q[3].w};
  int cnt = 0;
  #pragma unroll
  for (int j=0;j<16;j++) cnt += (vv[j] >= tau) ? 1 : 0;
  int inc = cnt;
  #pragma unroll
  for (int off=1; off<64; off<<=1){
    int t = __shfl_up(inc, off, 64);
    inc += (l >= off) ? t : 0;
  }
  int Ns = __shfl(inc, 63, 64);

  __shared__ unsigned long long sl[128];

  if (Ns <= 128){
    sl[l] = 0ull; sl[64+l] = 0ull;
    __syncthreads();
    int slot = inc - cnt;
    #pragma unroll
    for (int j=0;j<16;j++){
      if (vv[j] >= tau){
        int m = 4*l + 64*(j & ~3) + (j & 3);
        unsigned int mv = __float_as_uint(vv[j]);
        mv = (mv & 0x80000000u) ? ~mv : (mv | 0x80000000u);
        sl[slot] = ((unsigned long long)mv << 10) | (unsigned)(1023 - m);
        slot++;
      }
    }
    __syncthreads();
    if (Ns <= 64){
      unsigned long long key = sl[l];
      #pragma unroll
      for (int k=2; k<=64; k<<=1){
        #pragma unroll
        for (int j=k>>1; j>0; j>>=1){
          unsigned long long o = __shfl_xor(key, j, 64);
          bool a  = (l & k) == 0;
          bool bb = (l & j) == 0;
          unsigned long long mx = key > o ? key : o;
          unsigned long long mn = key > o ? o : key;
          key = (a == bb) ? mx : mn;
        }
      }
      if (l < 20) idx[out_base + l] = 1023 - (int)(key & 1023ull);
    } else {
      unsigned long long c0 = sl[l], c1 = sl[64+l];
      for (int kk=0; kk<20; kk++){
        unsigned long long m = c0 > c1 ? c0 : c1;
        #pragma unroll
        for (int off=32; off>0; off>>=1){
          unsigned long long o = __shfl_xor(m, off, 64);
          m = o > m ? o : m;
        }
        c0 = (c0 == m) ? 0ull : c0;
        c1 = (c1 == m) ? 0ull : c1;
        if (l == 0) idx[out_base + kk] = 1023 - (int)(m & 1023ull);
      }
    }
  } else {
    for (int kk=0; kk<20; kk++){
      float bv = NEGINIT; int bi = 0x3fffffff;
      #pragma unroll
      for (int j=0;j<16;j++){
        int m = 4*l + 64*(j & ~3) + (j & 3);
        if (vv[j] > bv || (vv[j] == bv && m < bi)){ bv = vv[j]; bi = m; }
      }
      #pragma unroll
      for (int off=32; off>0; off>>=1){
        float ov = __shfl_xor(bv, off, 64);
        int   oi = __shfl_xor(bi, off, 64);
        if (ov > bv || (ov == bv && oi < bi)){ bv = ov; bi = oi; }
      }
      #pragma unroll
      for (int j=0;j<16;j++){
        int m = 4*l + 64*(j & ~3) + (j & 3);
        vv[j] = (m == bi) ? REMOVED : vv[j];
      }
      if (l == 0) idx[out_base + kk] = bi;
    }
  }
}

// ---------------- edge epilogue: gather Y1 at neighbors, +center, scale/bias/lrelu, max_k
__global__ void k_edge(const float* __restrict__ Y, const int* __restrict__ idx,
    const float* __restrict__ g, const float* __restrict__ bias,
    float* __restrict__ out, int O, int ldo, int ooff){
  int row = blockIdx.x; int o = threadIdx.x; int b = row >> 10;
  __shared__ int js[20];
  if (threadIdx.x < 20) js[threadIdx.x] = idx[row*20 + threadIdx.x];
  __syncthreads();
  int O2 = O*2;
  float y1c = Y[(size_t)row*O2 + o];
  float d   = Y[(size_t)row*O2 + O + o] - y1c;
  float sc  = g[o] * INV_SQRT1P;
  float bb  = bias[o];
  const float* Yb = Y + ((size_t)(b<<10))*O2;
  float best = -1e38f;
  #pragma unroll
  for (int k=0;k<20;k++){
    float f = sc * (Yb[(size_t)js[k]*O2 + o] + d) + bb;
    best = fmaxf(best, lrelu(f));
  }
  out[(size_t)row*ldo + ooff + o] = best;
}

// ---------------- attention (16 batches) ----------------
__global__ __launch_bounds__(1024) void k_mean(const float* __restrict__ emb, float* __restrict__ m){
  int b = blockIdx.x; int f = threadIdx.x & 127; int ny = threadIdx.x >> 7;
  const float* e = emb + ((size_t)(b<<10) + ny*128)*128 + f;
  float s = 0.f;
  for (int n=0;n<128;n++) s += e[n*128];
  __shared__ float red[8][128];
  red[ny][f] = s;
  __syncthreads();
  if (ny == 0){
    float t = 0.f;
    #pragma unroll
    for (int i=0;i<8;i++) t += red[i][f];
    m[b*128+f] = t * (1.0f/1024.0f);
  }
}

__global__ __launch_bounds__(128) void k_gc(const float* __restrict__ m, const float* __restrict__ att_w,
     float* __restrict__ gc){
  int b = blockIdx.x, g = threadIdx.x;
  __shared__ float mr[128];
  mr[g] = m[b*128+g];
  __syncthreads();
  float s = 0.f;
  for (int f=0; f<128; f++) s += mr[f]*att_w[f*128+g];
  gc[b*128+g] = tanhf(s);
}

__global__ __launch_bounds__(64) void k_sc(const float* __restrict__ emb, const float* __restrict__ gc,
     float* __restrict__ sc, float* __restrict__ attout){
  int row = blockIdx.x; int l = threadIdx.x; int b = row >> 10;
  const float* e  = emb + (size_t)row*128;
  const float* gb = gc + b*128;
  float p = e[l]*gb[l] + e[l+64]*gb[l+64];
  #pragma unroll
  for (int off=32; off>0; off>>=1) p += __shfl_xor(p, off, 64);
  if (l == 0){
    float s = 1.0f/(1.0f + expf(-p));
    sc[row] = s;
    attout[row] = s;
  }
}

__global__ __launch_bounds__(1024) void k_pool(const float* __restrict__ emb, const float* __restrict__ sc,
     float* __restrict__ ep){
  int b = blockIdx.x; int f = threadIdx.x & 127; int ny = threadIdx.x >> 7;
  const float* e  = emb + ((size_t)(b<<10) + ny*128)*128 + f;
  const float* sb = sc + (b<<10) + ny*128;
  float s = 0.f;
  for (int n=0;n<128;n++) s += e[n*128]*sb[n];
  __shared__ float red[8][128];
  red[ny][f] = s;
  __syncthreads();
  if (ny == 0){
    float t = 0.f;
    #pragma unroll
    for (int i=0;i<8;i++) t += red[i][f];
    ep[b*128+f] = t;
  }
}

// ---------------- tensor network scoring ----------------
__global__ __launch_bounds__(256) void k_tnet(const float* __restrict__ e1, const float* __restrict__ e2,
    const float* __restrict__ tn_w, const float* __restrict__ tn_wb, const float* __restrict__ tn_bias,
    float* __restrict__ tsout){
  int b = blockIdx.x; int t = threadIdx.x; int tt = t & 15; int fs = t >> 4;
  __shared__ float E1[128], E2[128], red[16][17];
  if (t < 128){ E1[t] = e1[b*128+t]; E2[t] = e2[b*128+t]; }
  __syncthreads();
  float acc = 0.f;
  for (int f = fs*8; f < fs*8+8; f++){
    const float* tw = tn_w + f*128*16 + tt;
    float partial = 0.f;
    for (int g=0; g<128; g++) partial += E2[g]*tw[g*16];
    acc += E1[f]*partial;
  }
  red[fs][tt] = acc;
  __syncthreads();
  if (t < 16){
    float s = 0.f;
    #pragma unroll
    for (int i=0;i<16;i++) s += red[i][t];
    float acc2 = 0.f;
    for (int c=0;c<128;c++) acc2 += tn_wb[t*256+c]*E1[c] + tn_wb[t*256+128+c]*E2[c];
    float v = s + acc2 + tn_bias[t];
    tsout[b*16+t] = v > 0.f ? v : 0.f;
  }
}

__global__ __launch_bounds__(128) void k_score2(const float* __restrict__ ts,
   const float* __restrict__ fc1_w, const float* __restrict__ fc1_b,
   const float* __restrict__ sc_w, const float* __restrict__ sc_b, float* __restrict__ out){
  int t = threadIdx.x; int b = t >> 4, i = t & 15;
  __shared__ float h2[8][17];
  float a = 0.f;
  #pragma unroll
  for (int k=0;k<16;k++) a += ts[b*16+k]*fc1_w[i*16+k];
  a += fc1_b[i];
  h2[b][i] = a > 0.f ? a : 0.f;
  __syncthreads();
  if (t < 8){
    float s = 0.f;
    #pragma unroll
    for (int k=0;k<16;k++) s += h2[t][k]*sc_w[k];
    s += sc_b[0];
    out[t] = 1.0f/(1.0f + expf(-s));
  }
}

extern "C" void kernel_launch(void* const* d_in, const int* in_sizes, int n_in,
                              void* d_out, int out_size, void* d_ws, size_t ws_size,
                              hipStream_t stream){
  const float* f1  = (const float*)d_in[0];
  const float* f2  = (const float*)d_in[1];
  const float* sw1 = (const float*)d_in[2];  const float* sg1 = (const float*)d_in[3];  const float* sb1 = (const float*)d_in[4];
  const float* fw1 = (const float*)d_in[5];  const float* fg1 = (const float*)d_in[6];  const float* fb1 = (const float*)d_in[7];
  const float* sw2 = (const float*)d_in[8];  const float* sg2 = (const float*)d_in[9];  const float* sb2 = (const float*)d_in[10];
  const float* fw2 = (const float*)d_in[11]; const float* fg2 = (const float*)d_in[12]; const float* fb2 = (const float*)d_in[13];
  const float* sw3 = (const float*)d_in[14]; const float* sg3 = (const float*)d_in[15]; const float* sb3 = (const float*)d_in[16];
  const float* fw3 = (const float*)d_in[17]; const float* fg3 = (const float*)d_in[18]; const float* fb3 = (const float*)d_in[19];
  const float* ew  = (const float*)d_in[20]; const float* eg  = (const float*)d_in[21]; const float* eb  = (const float*)d_in[22];
  const float* att_w   = (const float*)d_in[23];
  const float* tn_w    = (const float*)d_in[24];
  const float* tn_wb   = (const float*)d_in[25];
  const float* tn_bias = (const float*)d_in[26];
  const float* fc1_w   = (const float*)d_in[27];
  const float* fc1_b   = (const float*)d_in[28];
  const float* sc_w    = (const float*)d_in[29];
  const float* sc_b    = (const float*)d_in[30];

  float* W    = (float*)d_ws;
  float* T0   = W;                  // 2,097,152  (16384 x <=128)
  float* T1   = W + 2097152;        // 2,097,152
  float* X3S3 = W + 4194304;        // 4,194,304  (16384 x 256)
  float* EMB  = W + 8388608;        // 2,097,152  (16384 x 128)
  float* xx   = W + 10485760;       // 16384
  float* mb   = W + 10502144;       // 2048
  float* gcb  = W + 10504192;       // 2048
  float* scb  = W + 10506240;       // 16384
  float* ep   = W + 10522624;       // 2048
  float* tsb  = W + 10524672;       // 128
  int*   idxb = (int*)(W + 10524800);            // 327680 ints
  unsigned short* PH = (unsigned short*)(W + 10852480); // packed frags hi (1M floats)
  unsigned short* PL = (unsigned short*)(W + 11901056); // packed frags lo (1M floats)
  float* REG  = W + 12949632;       // S: 16 x 1,048,576 = 16M floats; Y reuses (<=4M)

  (void)ws_size;
  float* out = (float*)d_out;

  auto edge = [&](const float* xin, int C, int O,
                  const float* w, const float* g, const float* bb,
                  float* xout, int ldo, int ooff){
    int Kp = (C + 15) & ~15;
    int nkc = Kp >> 4;
    k_xx<<<64, 256, 0, stream>>>(xin, xx, C);
    k_pack<<<(512*nkc*64+255)/256, 256, 0, stream>>>(xin, PH, PL, C, Kp);
    k_gsmf<<<2048, 256, 0, stream>>>(PH, PL, REG, xx, Kp);
    k_topk<<<16384, 64, 0, stream>>>(REG, idxb, 0);
    // Y reuses REG (stream order: topk consumed S already)
    k_gthin<<<dim3(2*O/64, 512, 1), 256, 0, stream>>>(xin, w, REG, C, 2*O,
          O, nullptr, nullptr, 0);
    k_edge<<<16384, O, 0, stream>>>(REG, idxb, g, bb, xout, O, ldo, ooff);
  };

  // xyz path (both point clouds as batches 0-7 / 8-15)
  k_extract<<<(8*3*1024+255)/256, 256, 0, stream>>>(f1, T0, 0, 3, 0);
  k_extract<<<(8*3*1024+255)/256, 256, 0, stream>>>(f2, T0, 0, 3, 8);
  edge(T0, 3,   64, sw1, sg1, sb1, T1, 64, 0);
  edge(T1, 64,  64, sw2, sg2, sb2, T0, 64, 0);
  edge(T0, 64, 128, sw3, sg3, sb3, X3S3, 256, 0);    // x3 -> cols 0..127
  // sem path
  k_extract<<<(8*128*1024+255)/256, 256, 0, stream>>>(f1, T0, 3, 128, 0);
  k_extract<<<(8*128*1024+255)/256, 256, 0, stream>>>(f2, T0, 3, 128, 8);
  edge(T0, 128, 64, fw1, fg1, fb1, T1, 64, 0);
  edge(T1, 64,  64, fw2, fg2, fb2, T0, 64, 0);
  edge(T0, 64, 128, fw3, fg3, fb3, X3S3, 256, 128);  // s3 -> cols 128..255
  // combine: emb = lrelu(eg * (X3S3 @ ew^T)/sqrt(1+eps) + eb)
  k_gthin<<<dim3(2, 512, 1), 256, 0, stream>>>(X3S3, ew, EMB, 256, 128,
        0, eg, eb, 1);
  // attention over all 16 batches
  k_mean<<<16, 1024, 0, stream>>>(EMB, mb);
  k_gc<<<16, 128, 0, stream>>>(mb, att_w, gcb);
  k_sc<<<16384, 64, 0, stream>>>(EMB, gcb, scb, out + 8);
  k_pool<<<16, 1024, 0, stream>>>(EMB, scb, ep);

  k_tnet<<<8, 256, 0, stream>>>(ep, ep + 1024, tn_w, tn_wb, tn_bias, tsb);
  k_score2<<<1, 128, 0, stream>>>(tsb, fc1_w, fc1_b, sc_w, sc_b, out);
}

// Round 16
// 653.784 us; speedup vs baseline: 2.4441x; 1.0352x over previous
//
#include <hip/hip_runtime.h>
#include <math.h>

#define INV_SQRT1P 0.99999500003749968754f   // 1/sqrt(1+1e-5)
#define REMOVED  -2.0e38f
#define NEGINIT  -3.0e38f

typedef short v8s  __attribute__((ext_vector_type(8)));
typedef float v16f __attribute__((ext_vector_type(16)));

static __device__ __forceinline__ float lrelu(float f){ return f >= 0.0f ? f : 0.2f*f; }

// ---------------- extract channels: feat (8,131,1024) -> rows [boff*1024..) (N,Cout) ----
__global__ void k_extract(const float* __restrict__ f, float* __restrict__ out, int c0, int Cout, int boff){
  int i = blockIdx.x*256 + threadIdx.x;
  int total = 8*Cout*1024;
  if (i >= total) return;
  int n  = i & 1023;
  int bc = i >> 10;
  int c  = bc % Cout;
  int b  = bc / Cout;
  out[((size_t)(((b+boff)<<10)+n))*Cout + c] = f[((size_t)(b*131 + c0 + c) << 10) + n];
}

// ---------------- row sum of squares: x (16384,C) -> xx (16384) ----------------
__global__ void k_xx(const float* __restrict__ x, float* __restrict__ xx, int C){
  int r = blockIdx.x*256 + threadIdx.x;
  if (r >= 16384) return;
  const float* xr = x + (size_t)r*C;
  float s = 0.f;
  for (int c=0;c<C;c++) s += xr[c]*xr[c];
  xx[r] = s;
}

// ---------------- pack fp32 X into MFMA-fragment-major bf16 hi/lo ----------------
__global__ void k_pack(const float* __restrict__ X, unsigned short* __restrict__ PH,
                       unsigned short* __restrict__ PL, int C, int Kp){
  int gid = blockIdx.x*256 + threadIdx.x;
  int nkc = Kp >> 4;
  if (gid >= 512*nkc*64) return;
  int lane = gid & 63;
  int chunk = gid >> 6;
  int rb = chunk / nkc, kc = chunk - rb*nkc;
  int row = rb*32 + (lane & 31);
  int k0 = kc*16 + ((lane>>5)<<3);
  unsigned short h[8], lo[8];
  const float* Xr = X + (size_t)row*C;
  #pragma unroll
  for (int j=0;j<8;j++){
    int k = k0 + j;
    float x = (k < C) ? Xr[k] : 0.f;
    unsigned u = __float_as_uint(x);
    unsigned h16 = (u + 0x7fffu + ((u>>16)&1u)) >> 16;
    float hf = __uint_as_float(h16 << 16);
    float lf = x - hf;
    unsigned ul = __float_as_uint(lf);
    unsigned l16 = (ul + 0x7fffu + ((ul>>16)&1u)) >> 16;
    h[j] = (unsigned short)h16; lo[j] = (unsigned short)l16;
  }
  size_t o = (size_t)chunk*512 + lane*8;
  *(v8s*)(PH + o) = *(v8s*)h;
  *(v8s*)(PL + o) = *(v8s*)lo;
}

// ---------------- pack conv weight (O,2C) -> fragment-major bf16 hi/lo (2O x Kp) ------
__global__ void k_wpack(const float* __restrict__ Wm, unsigned short* __restrict__ PWH,
                        unsigned short* __restrict__ PWL, int C, int Kp, int O){
  int gid = blockIdx.x*256 + threadIdx.x;
  int nkc = Kp >> 4;
  int nchunk = (2*O/32)*nkc;
  if (gid >= nchunk*64) return;
  int lane = gid & 63;
  int chunk = gid >> 6;
  int jb = chunk / nkc, kc = chunk - jb*nkc;
  int j = jb*32 + (lane & 31);
  int k0 = kc*16 + ((lane>>5)<<3);
  unsigned short h[8], lo[8];
  #pragma unroll
  for (int t=0;t<8;t++){
    int k = k0 + t;
    float x = 0.f;
    if (k < C) x = (j < O) ? Wm[(size_t)j*2*C + k] : Wm[(size_t)(j-O)*2*C + C + k];
    unsigned u = __float_as_uint(x);
    unsigned h16 = (u + 0x7fffu + ((u>>16)&1u)) >> 16;
    float hf = __uint_as_float(h16 << 16);
    float lf = x - hf;
    unsigned ul = __float_as_uint(lf);
    unsigned l16 = (ul + 0x7fffu + ((ul>>16)&1u)) >> 16;
    h[t] = (unsigned short)h16; lo[t] = (unsigned short)l16;
  }
  size_t o = (size_t)chunk*512 + lane*8;
  *(v8s*)(PWH + o) = *(v8s*)h;
  *(v8s*)(PWL + o) = *(v8s*)lo;
}

// ---------------- S = neg_d via bf16x3-split MFMA, packed fragments --------------
// Wave computes 32 rows x 64 cols; C/D layout: col=lane&31, row=(r&3)+8*(r>>2)+4*(l>>5).
__global__ __launch_bounds__(256) void k_gsmf(const unsigned short* __restrict__ PH,
    const unsigned short* __restrict__ PL, float* __restrict__ S,
    const float* __restrict__ xx, int Kp){
  int w = threadIdx.x >> 6;
  int l = threadIdx.x & 63;
  int gw = blockIdx.x*4 + w;
  int batch = gw >> 9;
  int t = gw & 511;
  int tm = t >> 4, tp = t & 15;
  int nkc = Kp >> 4;
  int rbm = batch*32 + tm;
  int cb0 = batch*32 + 2*tp, cb1 = cb0 + 1;
  size_t ao  = ((size_t)rbm*nkc)*512 + l*8;
  size_t b0o = ((size_t)cb0*nkc)*512 + l*8;
  size_t b1o = ((size_t)cb1*nkc)*512 + l*8;
  v16f acc0, acc1;
  #pragma unroll
  for (int i=0;i<16;i++){ acc0[i] = 0.f; acc1[i] = 0.f; }
  for (int kc=0; kc<nkc; kc++){
    v8s Ah  = *(const v8s*)(PH + ao);
    v8s Al  = *(const v8s*)(PL + ao);
    v8s B0h = *(const v8s*)(PH + b0o);
    v8s B0l = *(const v8s*)(PL + b0o);
    v8s B1h = *(const v8s*)(PH + b1o);
    v8s B1l = *(const v8s*)(PL + b1o);
    acc0 = __builtin_amdgcn_mfma_f32_32x32x16_bf16(Ah, B0h, acc0, 0, 0, 0);
    acc1 = __builtin_amdgcn_mfma_f32_32x32x16_bf16(Ah, B1h, acc1, 0, 0, 0);
    acc0 = __builtin_amdgcn_mfma_f32_32x32x16_bf16(Ah, B0l, acc0, 0, 0, 0);
    acc1 = __builtin_amdgcn_mfma_f32_32x32x16_bf16(Ah, B1l, acc1, 0, 0, 0);
    acc0 = __builtin_amdgcn_mfma_f32_32x32x16_bf16(Al, B0h, acc0, 0, 0, 0);
    acc1 = __builtin_amdgcn_mfma_f32_32x32x16_bf16(Al, B1h, acc1, 0, 0, 0);
    ao += 512; b0o += 512; b1o += 512;
  }
  const float* xxb = xx + (batch<<10);
  int rbase = tm*32, cbase0 = tp*64, cbase1 = tp*64 + 32;
  float xc0 = xxb[cbase0 + (l & 31)];
  float xc1 = xxb[cbase1 + (l & 31)];
  float* Sb = S + (size_t)batch*1048576;
  #pragma unroll
  for (int r=0;r<16;r++){
    int rl_ = (r&3) + ((r>>2)<<3) + ((l>>5)<<2);
    float xr = xxb[rbase + rl_];
    Sb[(size_t)(rbase + rl_)*1024 + cbase0 + (l&31)] = 2.f*acc0[r] - xr - xc0;
    Sb[(size_t)(rbase + rl_)*1024 + cbase1 + (l&31)] = 2.f*acc1[r] - xr - xc1;
  }
}

// ---------------- Y = X . Wp^T via bf16x3-split MFMA, packed fragments --------------
// Wave computes 32 rows x 64 cols of Y (16384 x 2O), row-major store.
__global__ __launch_bounds__(256) void k_ymf(const unsigned short* __restrict__ PH,
    const unsigned short* __restrict__ PL, const unsigned short* __restrict__ PWH,
    const unsigned short* __restrict__ PWL, float* __restrict__ Y, int Kp, int N, int npair){
  int w = threadIdx.x >> 6;
  int l = threadIdx.x & 63;
  int gw = blockIdx.x*4 + w;
  int mt = gw / npair;
  int pair = gw - mt*npair;
  int nkc = Kp >> 4;
  int jb0 = pair*2, jb1 = pair*2 + 1;
  size_t ao  = ((size_t)mt*nkc)*512 + l*8;
  size_t b0o = ((size_t)jb0*nkc)*512 + l*8;
  size_t b1o = ((size_t)jb1*nkc)*512 + l*8;
  v16f acc0, acc1;
  #pragma unroll
  for (int i=0;i<16;i++){ acc0[i] = 0.f; acc1[i] = 0.f; }
  for (int kc=0; kc<nkc; kc++){
    v8s Ah  = *(const v8s*)(PH + ao);
    v8s Al  = *(const v8s*)(PL + ao);
    v8s B0h = *(const v8s*)(PWH + b0o);
    v8s B0l = *(const v8s*)(PWL + b0o);
    v8s B1h = *(const v8s*)(PWH + b1o);
    v8s B1l = *(const v8s*)(PWL + b1o);
    acc0 = __builtin_amdgcn_mfma_f32_32x32x16_bf16(Ah, B0h, acc0, 0, 0, 0);
    acc1 = __builtin_amdgcn_mfma_f32_32x32x16_bf16(Ah, B1h, acc1, 0, 0, 0);
    acc0 = __builtin_amdgcn_mfma_f32_32x32x16_bf16(Ah, B0l, acc0, 0, 0, 0);
    acc1 = __builtin_amdgcn_mfma_f32_32x32x16_bf16(Ah, B1l, acc1, 0, 0, 0);
    acc0 = __builtin_amdgcn_mfma_f32_32x32x16_bf16(Al, B0h, acc0, 0, 0, 0);
    acc1 = __builtin_amdgcn_mfma_f32_32x32x16_bf16(Al, B1h, acc1, 0, 0, 0);
    ao += 512; b0o += 512; b1o += 512;
  }
  int rbase = mt*32;
  int c0 = pair*64 + (l & 31), c1 = c0 + 32;
  #pragma unroll
  for (int r=0;r<16;r++){
    int rl_ = (r&3) + ((r>>2)<<3) + ((l>>5)<<2);
    float* dst = Y + (size_t)(rbase + rl_)*N;
    dst[c0] = acc0[r];
    dst[c1] = acc1[r];
  }
}

// ---------------- top-20: 4 waves per block, 1 row per wave, no barriers -------------
__global__ __launch_bounds__(256) void k_topk4(const float* __restrict__ S,
      int* __restrict__ idx){
  int wave = threadIdx.x >> 6;
  int l = threadIdx.x & 63;
  int rl = blockIdx.x*4 + wave;
  const float4* Srow = (const float4*)(S + (size_t)rl*1024);
  float4 q[4];
  #pragma unroll
  for (int j=0;j<4;j++) q[j] = Srow[l + 64*j];
  int out_base = rl*20;

  float lmax = fmaxf(fmaxf(fmaxf(q[0].x,q[0].y),fmaxf(q[0].z,q[0].w)),
               fmaxf(fmaxf(fmaxf(q[1].x,q[1].y),fmaxf(q[1].z,q[1].w)),
               fmaxf(fmaxf(fmaxf(q[2].x,q[2].y),fmaxf(q[2].z,q[2].w)),
                     fmaxf(fmaxf(q[3].x,q[3].y),fmaxf(q[3].z,q[3].w)))));

  float sv = lmax;
  #pragma unroll
  for (int k=2; k<=64; k<<=1){
    #pragma unroll
    for (int j=k>>1; j>0; j>>=1){
      float o = __shfl_xor(sv, j, 64);
      bool a  = (l & k) == 0;
      bool bb = (l & j) == 0;
      sv = (a == bb) ? fminf(sv, o) : fmaxf(sv, o);
    }
  }
  float tau = __shfl(sv, 44, 64);

  float vv[16] = {q[0].x,q[0].y,q[0].z,q[0].w, q[1].x,q[1].y,q[1].z,q[1].w,
                  q[2].x,q[2].y,q[2].z,q[2].w, q[3].x,q[3].y,q[3].z,q[3].w};
  int cnt = 0;
  #pragma unroll
  for (int j=0;j<16;j++) cnt += (vv[j] >= tau) ? 1 : 0;
  int inc = cnt;
  #pragma unroll
  for (int off=1; off<64; off<<=1){
    int t = __shfl_up(inc, off, 64);
    inc += (l >= off) ? t : 0;
  }
  int Ns = __shfl(inc, 63, 64);

  __shared__ unsigned long long slb[4][128];
  unsigned long long* sl = slb[wave];     // wave-private: no barriers needed

  if (Ns <= 128){
    sl[l] = 0ull; sl[64+l] = 0ull;
    int slot = inc - cnt;
    #pragma unroll
    for (int j=0;j<16;j++){
      if (vv[j] >= tau){
        int m = 4*l + 64*(j & ~3) + (j & 3);
        unsigned int mv = __float_as_uint(vv[j]);
        mv = (mv & 0x80000000u) ? ~mv : (mv | 0x80000000u);
        sl[slot] = ((unsigned long long)mv << 10) | (unsigned)(1023 - m);
        slot++;
      }
    }
    if (Ns <= 64){
      unsigned long long key = sl[l];
      #pragma unroll
      for (int k=2; k<=64; k<<=1){
        #pragma unroll
        for (int j=k>>1; j>0; j>>=1){
          unsigned long long o = __shfl_xor(key, j, 64);
          bool a  = (l & k) == 0;
          bool bb = (l & j) == 0;
          unsigned long long mx = key > o ? key : o;
          unsigned long long mn = key > o ? o : key;
          key = (a == bb) ? mx : mn;
        }
      }
      if (l < 20) idx[out_base + l] = 1023 - (int)(key & 1023ull);
    } else {
      unsigned long long c0 = sl[l], c1 = sl[64+l];
      for (int kk=0; kk<20; kk++){
        unsigned long long m = c0 > c1 ? c0 : c1;
        #pragma unroll
        for (int off=32; off>0; off>>=1){
          unsigned long long o = __shfl_xor(m, off, 64);
          m = o > m ? o : m;
        }
        c0 = (c0 == m) ? 0ull : c0;
        c1 = (c1 == m) ? 0ull : c1;
        if (l == 0) idx[out_base + kk] = 1023 - (int)(m & 1023ull);
      }
    }
  } else {
    for (int kk=0; kk<20; kk++){
      float bv = NEGINIT; int bi = 0x3fffffff;
      #pragma unroll
      for (int j=0;j<16;j++){
        int m = 4*l + 64*(j & ~3) + (j & 3);
        if (vv[j] > bv || (vv[j] == bv && m < bi)){ bv = vv[j]; bi = m; }
      }
      #pragma unroll
      for (int off=32; off>0; off>>=1){
        float ov = __shfl_xor(bv, off, 64);
        int   oi = __shfl_xor(bi, off, 64);
        if (ov > bv || (ov == bv && oi < bi)){ bv = ov; bi = oi; }
      }
      #pragma unroll
      for (int j=0;j<16;j++){
        int m = 4*l + 64*(j & ~3) + (j & 3);
        vv[j] = (m == bi) ? REMOVED : vv[j];
      }
      if (l == 0) idx[out_base + kk] = bi;
    }
  }
}

// ---------------- thin NT GEMM (kept for the emb combine) ----------------
__global__ __launch_bounds__(256) void k_gthin(
    const float* __restrict__ Am, const float* __restrict__ Bm, float* __restrict__ Om,
    int K, int ldo, int wmode, const float* __restrict__ p1, const float* __restrict__ p2, int ep)
{
  __shared__ float As[64][33];
  __shared__ float Bs[64][68];
  int tid = threadIdx.x;
  int tx = tid & 15, ty = tid >> 4;
  int rbase = blockIdx.y*32, cbase = blockIdx.x*64;
  float acc[2][4];
  #pragma unroll
  for (int i=0;i<2;i++){ acc[i][0]=0.f; acc[i][1]=0.f; acc[i][2]=0.f; acc[i][3]=0.f; }

  for (int c0=0; c0<K; c0+=64){
    int cw = K - c0; if (cw > 64) cw = 64;
    #pragma unroll
    for (int p=0; p<2; p++){
      int idx = p*256 + tid;
      int kq = idx & 15, row = idx >> 4;
      const float* src = Am + (size_t)(rbase+row)*K + c0 + kq*4;
      float4 v = {0.f,0.f,0.f,0.f};
      if (kq*4 + 4 <= cw) v = *(const float4*)src;
      else {
        if (kq*4+0 < cw) v.x = src[0];
        if (kq*4+1 < cw) v.y = src[1];
        if (kq*4+2 < cw) v.z = src[2];
        if (kq*4+3 < cw) v.w = src[3];
      }
      As[kq*4+0][row]=v.x; As[kq*4+1][row]=v.y; As[kq*4+2][row]=v.z; As[kq*4+3][row]=v.w;
    }
    #pragma unroll
    for (int p=0; p<4; p++){
      int idx = p*256 + tid;
      int kq = idx & 15, col = idx >> 4;
      int j = cbase + col;
      const float* src = (wmode > 0)
          ? ((j < wmode) ? Bm + (size_t)j*2*K + c0 + kq*4
                         : Bm + (size_t)(j-wmode)*2*K + K + c0 + kq*4)
          : Bm + (size_t)j*K + c0 + kq*4;
      float4 v = {0.f,0.f,0.f,0.f};
      if (kq*4 + 4 <= cw) v = *(const float4*)src;
      else {
        if (kq*4+0 < cw) v.x = src[0];
        if (kq*4+1 < cw) v.y = src[1];
        if (kq*4+2 < cw) v.z = src[2];
        if (kq*4+3 < cw) v.w = src[3];
      }
      int swb = (kq & 14) << 1;
      int cs = col ^ swb;
      Bs[kq*4+0][cs]=v.x; Bs[kq*4+1][cs]=v.y; Bs[kq*4+2][cs]=v.z; Bs[kq*4+3][cs]=v.w;
    }
    __syncthreads();
    for (int k=0;k<cw;k++){
      int sw = ((k>>3)&7)<<2;
      float a0 = As[k][ty*2], a1 = As[k][ty*2+1];
      float b[4];
      *(float4*)b = *(const float4*)&Bs[k][(tx*4) ^ sw];
      acc[0][0]+=a0*b[0]; acc[0][1]+=a0*b[1]; acc[0][2]+=a0*b[2]; acc[0][3]+=a0*b[3];
      acc[1][0]+=a1*b[0]; acc[1][1]+=a1*b[1]; acc[1][2]+=a1*b[2]; acc[1][3]+=a1*b[3];
    }
    __syncthreads();
  }
  #pragma unroll
  for (int i=0;i<2;i++){
    int r = rbase + ty*2 + i;
    float o[4];
    #pragma unroll
    for (int j=0;j<4;j++){
      int cc = cbase + tx*4 + j;
      float v = acc[i][j];
      if (ep == 1) v = lrelu(p1[cc]*v*INV_SQRT1P + p2[cc]);
      o[j] = v;
    }
    *(float4*)(Om + (size_t)r*ldo + cbase + tx*4) = *(float4*)o;
  }
}

// ---------------- edge epilogue, multi-row blocks (256 threads) ----------------
__global__ __launch_bounds__(256) void k_edge(const float* __restrict__ Y, const int* __restrict__ idx,
    const float* __restrict__ g, const float* __restrict__ bias,
    float* __restrict__ out, int O, int ldo, int ooff){
  int rpb = 256/O;
  int rloc = threadIdx.x/O;
  int o = threadIdx.x - rloc*O;
  int row = blockIdx.x*rpb + rloc;
  int b = row >> 10;
  __shared__ int js[4][20];
  int nj = rpb*20;
  if (threadIdx.x < nj) js[threadIdx.x/20][threadIdx.x%20] = idx[(blockIdx.x*rpb)*20 + threadIdx.x];
  __syncthreads();
  int O2 = O*2;
  float y1c = Y[(size_t)row*O2 + o];
  float d   = Y[(size_t)row*O2 + O + o] - y1c;
  float sc  = g[o] * INV_SQRT1P;
  float bb  = bias[o];
  const float* Yb = Y + ((size_t)(b<<10))*O2;
  float best = -1e38f;
  #pragma unroll
  for (int k=0;k<20;k++){
    float f = sc * (Yb[(size_t)js[rloc][k]*O2 + o] + d) + bb;
    best = fmaxf(best, lrelu(f));
  }
  out[(size_t)row*ldo + ooff + o] = best;
}

// ---------------- attention (16 batches) ----------------
__global__ __launch_bounds__(1024) void k_mean(const float* __restrict__ emb, float* __restrict__ m){
  int b = blockIdx.x; int f = threadIdx.x & 127; int ny = threadIdx.x >> 7;
  const float* e = emb + ((size_t)(b<<10) + ny*128)*128 + f;
  float s = 0.f;
  for (int n=0;n<128;n++) s += e[n*128];
  __shared__ float red[8][128];
  red[ny][f] = s;
  __syncthreads();
  if (ny == 0){
    float t = 0.f;
    #pragma unroll
    for (int i=0;i<8;i++) t += red[i][f];
    m[b*128+f] = t * (1.0f/1024.0f);
  }
}

__global__ __launch_bounds__(128) void k_gc(const float* __restrict__ m, const float* __restrict__ att_w,
     float* __restrict__ gc){
  int b = blockIdx.x, g = threadIdx.x;
  __shared__ float mr[128];
  mr[g] = m[b*128+g];
  __syncthreads();
  float s = 0.f;
  for (int f=0; f<128; f++) s += mr[f]*att_w[f*128+g];
  gc[b*128+g] = tanhf(s);
}

__global__ __launch_bounds__(64) void k_sc(const float* __restrict__ emb, const float* __restrict__ gc,
     float* __restrict__ sc, float* __restrict__ attout){
  int row = blockIdx.x; int l = threadIdx.x; int b = row >> 10;
  const float* e  = emb + (size_t)row*128;
  const float* gb = gc + b*128;
  float p = e[l]*gb[l] + e[l+64]*gb[l+64];
  #pragma unroll
  for (int off=32; off>0; off>>=1) p += __shfl_xor(p, off, 64);
  if (l == 0){
    float s = 1.0f/(1.0f + expf(-p));
    sc[row] = s;
    attout[row] = s;
  }
}

__global__ __launch_bounds__(1024) void k_pool(const float* __restrict__ emb, const float* __restrict__ sc,
     float* __restrict__ ep){
  int b = blockIdx.x; int f = threadIdx.x & 127; int ny = threadIdx.x >> 7;
  const float* e  = emb + ((size_t)(b<<10) + ny*128)*128 + f;
  const float* sb = sc + (b<<10) + ny*128;
  float s = 0.f;
  for (int n=0;n<128;n++) s += e[n*128]*sb[n];
  __shared__ float red[8][128];
  red[ny][f] = s;
  __syncthreads();
  if (ny == 0){
    float t = 0.f;
    #pragma unroll
    for (int i=0;i<8;i++) t += red[i][f];
    ep[b*128+f] = t;
  }
}

// ---------------- tensor network scoring ----------------
__global__ __launch_bounds__(256) void k_tnet(const float* __restrict__ e1, const float* __restrict__ e2,
    const float* __restrict__ tn_w, const float* __restrict__ tn_wb, const float* __restrict__ tn_bias,
    float* __restrict__ tsout){
  int b = blockIdx.x; int t = threadIdx.x; int tt = t & 15; int fs = t >> 4;
  __shared__ float E1[128], E2[128], red[16][17];
  if (t < 128){ E1[t] = e1[b*128+t]; E2[t] = e2[b*128+t]; }
  __syncthreads();
  float acc = 0.f;
  for (int f = fs*8; f < fs*8+8; f++){
    const float* tw = tn_w + f*128*16 + tt;
    float partial = 0.f;
    for (int g=0; g<128; g++) partial += E2[g]*tw[g*16];
    acc += E1[f]*partial;
  }
  red[fs][tt] = acc;
  __syncthreads();
  if (t < 16){
    float s = 0.f;
    #pragma unroll
    for (int i=0;i<16;i++) s += red[i][t];
    float acc2 = 0.f;
    for (int c=0;c<128;c++) acc2 += tn_wb[t*256+c]*E1[c] + tn_wb[t*256+128+c]*E2[c];
    float v = s + acc2 + tn_bias[t];
    tsout[b*16+t] = v > 0.f ? v : 0.f;
  }
}

__global__ __launch_bounds__(128) void k_score2(const float* __restrict__ ts,
   const float* __restrict__ fc1_w, const float* __restrict__ fc1_b,
   const float* __restrict__ sc_w, const float* __restrict__ sc_b, float* __restrict__ out){
  int t = threadIdx.x; int b = t >> 4, i = t & 15;
  __shared__ float h2[8][17];
  float a = 0.f;
  #pragma unroll
  for (int k=0;k<16;k++) a += ts[b*16+k]*fc1_w[i*16+k];
  a += fc1_b[i];
  h2[b][i] = a > 0.f ? a : 0.f;
  __syncthreads();
  if (t < 8){
    float s = 0.f;
    #pragma unroll
    for (int k=0;k<16;k++) s += h2[t][k]*sc_w[k];
    s += sc_b[0];
    out[t] = 1.0f/(1.0f + expf(-s));
  }
}

extern "C" void kernel_launch(void* const* d_in, const int* in_sizes, int n_in,
                              void* d_out, int out_size, void* d_ws, size_t ws_size,
                              hipStream_t stream){
  const float* f1  = (const float*)d_in[0];
  const float* f2  = (const float*)d_in[1];
  const float* sw1 = (const float*)d_in[2];  const float* sg1 = (const float*)d_in[3];  const float* sb1 = (const float*)d_in[4];
  const float* fw1 = (const float*)d_in[5];  const float* fg1 = (const float*)d_in[6];  const float* fb1 = (const float*)d_in[7];
  const float* sw2 = (const float*)d_in[8];  const float* sg2 = (const float*)d_in[9];  const float* sb2 = (const float*)d_in[10];
  const float* fw2 = (const float*)d_in[11]; const float* fg2 = (const float*)d_in[12]; const float* fb2 = (const float*)d_in[13];
  const float* sw3 = (const float*)d_in[14]; const float* sg3 = (const float*)d_in[15]; const float* sb3 = (const float*)d_in[16];
  const float* fw3 = (const float*)d_in[17]; const float* fg3 = (const float*)d_in[18]; const float* fb3 = (const float*)d_in[19];
  const float* ew  = (const float*)d_in[20]; const float* eg  = (const float*)d_in[21]; const float* eb  = (const float*)d_in[22];
  const float* att_w   = (const float*)d_in[23];
  const float* tn_w    = (const float*)d_in[24];
  const float* tn_wb   = (const float*)d_in[25];
  const float* tn_bias = (const float*)d_in[26];
  const float* fc1_w   = (const float*)d_in[27];
  const float* fc1_b   = (const float*)d_in[28];
  const float* sc_w    = (const float*)d_in[29];
  const float* sc_b    = (const float*)d_in[30];

  float* W    = (float*)d_ws;
  float* T0   = W;                  // 2,097,152  (16384 x <=128)
  float* T1   = W + 2097152;        // 2,097,152
  float* X3S3 = W + 4194304;        // 4,194,304  (16384 x 256)
  float* EMB  = W + 8388608;        // 2,097,152  (16384 x 128)
  float* xx   = W + 10485760;       // 16384
  float* mb   = W + 10502144;       // 2048
  float* gcb  = W + 10504192;       // 2048
  float* scb  = W + 10506240;       // 16384
  float* ep   = W + 10522624;       // 2048
  float* tsb  = W + 10524672;       // 128
  int*   idxb = (int*)(W + 10524800);            // 327680 ints
  unsigned short* PH = (unsigned short*)(W + 10852480); // packed frags hi (1M floats)
  unsigned short* PL = (unsigned short*)(W + 11901056); // packed frags lo (1M floats)
  unsigned short* PWH = (unsigned short*)(W + 12949632); // packed weight hi (16K floats)
  unsigned short* PWL = (unsigned short*)(W + 12966016); // packed weight lo (16K floats)
  float* REG  = W + 12982400;       // S: 16M floats; Y reuses (<=4M)

  (void)ws_size;
  float* out = (float*)d_out;

  auto edge = [&](const float* xin, int C, int O,
                  const float* w, const float* g, const float* bb,
                  float* xout, int ldo, int ooff){
    int Kp = (C + 15) & ~15;
    int nkc = Kp >> 4;
    int npair = 2*O/64;
    k_xx<<<64, 256, 0, stream>>>(xin, xx, C);
    k_pack<<<(512*nkc*64+255)/256, 256, 0, stream>>>(xin, PH, PL, C, Kp);
    k_wpack<<<((2*O/32)*nkc*64+255)/256, 256, 0, stream>>>(w, PWH, PWL, C, Kp, O);
    k_gsmf<<<2048, 256, 0, stream>>>(PH, PL, REG, xx, Kp);
    k_topk4<<<4096, 256, 0, stream>>>(REG, idxb);
    // Y reuses REG (topk consumed S already, stream-ordered)
    k_ymf<<<128*npair, 256, 0, stream>>>(PH, PL, PWH, PWL, REG, Kp, 2*O, npair);
    k_edge<<<16384/(256/O), 256, 0, stream>>>(REG, idxb, g, bb, xout, O, ldo, ooff);
  };

  // xyz path (both point clouds as batches 0-7 / 8-15)
  k_extract<<<(8*3*1024+255)/256, 256, 0, stream>>>(f1, T0, 0, 3, 0);
  k_extract<<<(8*3*1024+255)/256, 256, 0, stream>>>(f2, T0, 0, 3, 8);
  edge(T0, 3,   64, sw1, sg1, sb1, T1, 64, 0);
  edge(T1, 64,  64, sw2, sg2, sb2, T0, 64, 0);
  edge(T0, 64, 128, sw3, sg3, sb3, X3S3, 256, 0);    // x3 -> cols 0..127
  // sem path
  k_extract<<<(8*128*1024+255)/256, 256, 0, stream>>>(f1, T0, 3, 128, 0);
  k_extract<<<(8*128*1024+255)/256, 256, 0, stream>>>(f2, T0, 3, 128, 8);
  edge(T0, 128, 64, fw1, fg1, fb1, T1, 64, 0);
  edge(T1, 64,  64, fw2, fg2, fb2, T0, 64, 0);
  edge(T0, 64, 128, fw3, fg3, fb3, X3S3, 256, 128);  // s3 -> cols 128..255
  // combine: emb = lrelu(eg * (X3S3 @ ew^T)/sqrt(1+eps) + eb)
  k_gthin<<<dim3(2, 512, 1), 256, 0, stream>>>(X3S3, ew, EMB, 256, 128,
        0, eg, eb, 1);
  // attention over all 16 batches
  k_mean<<<16, 1024, 0, stream>>>(EMB, mb);
  k_gc<<<16, 128, 0, stream>>>(mb, att_w, gcb);
  k_sc<<<16384, 64, 0, stream>>>(EMB, gcb, scb, out + 8);
  k_pool<<<16, 1024, 0, stream>>>(EMB, scb, ep);

  k_tnet<<<8, 256, 0, stream>>>(ep, ep + 1024, tn_w, tn_wb, tn_bias, tsb);
  k_score2<<<1, 128, 0, stream>>>(tsb, fc1_w, fc1_b, sc_w, sc_b, out);
}

// Round 17
// 601.328 us; speedup vs baseline: 2.6573x; 1.0872x over previous
//
#include <hip/hip_runtime.h>
#include <math.h>

#define INV_SQRT1P 0.99999500003749968754f   // 1/sqrt(1+1e-5)
#define REMOVED  -2.0e38f
#define NEGINIT  -3.0e38f

typedef short v8s  __attribute__((ext_vector_type(8)));
typedef float v16f __attribute__((ext_vector_type(16)));

static __device__ __forceinline__ float lrelu(float f){ return f >= 0.0f ? f : 0.2f*f; }

// ---------------- extract channels: feat (8,131,1024) -> rows [boff*1024..) (N,Cout) ----
__global__ void k_extract(const float* __restrict__ f, float* __restrict__ out, int c0, int Cout, int boff){
  int i = blockIdx.x*256 + threadIdx.x;
  int total = 8*Cout*1024;
  if (i >= total) return;
  int n  = i & 1023;
  int bc = i >> 10;
  int c  = bc % Cout;
  int b  = bc / Cout;
  out[((size_t)(((b+boff)<<10)+n))*Cout + c] = f[((size_t)(b*131 + c0 + c) << 10) + n];
}

// ---------------- row sum of squares: x (16384,C) -> xx (16384) ----------------
__global__ void k_xx(const float* __restrict__ x, float* __restrict__ xx, int C){
  int r = blockIdx.x*256 + threadIdx.x;
  if (r >= 16384) return;
  const float* xr = x + (size_t)r*C;
  float s = 0.f;
  for (int c=0;c<C;c++) s += xr[c]*xr[c];
  xx[r] = s;
}

// ---------------- pack fp32 X into MFMA-fragment-major bf16 hi/lo ----------------
__global__ void k_pack(const float* __restrict__ X, unsigned short* __restrict__ PH,
                       unsigned short* __restrict__ PL, int C, int Kp){
  int gid = blockIdx.x*256 + threadIdx.x;
  int nkc = Kp >> 4;
  if (gid >= 512*nkc*64) return;
  int lane = gid & 63;
  int chunk = gid >> 6;
  int rb = chunk / nkc, kc = chunk - rb*nkc;
  int row = rb*32 + (lane & 31);
  int k0 = kc*16 + ((lane>>5)<<3);
  unsigned short h[8], lo[8];
  const float* Xr = X + (size_t)row*C;
  #pragma unroll
  for (int j=0;j<8;j++){
    int k = k0 + j;
    float x = (k < C) ? Xr[k] : 0.f;
    unsigned u = __float_as_uint(x);
    unsigned h16 = (u + 0x7fffu + ((u>>16)&1u)) >> 16;
    float hf = __uint_as_float(h16 << 16);
    float lf = x - hf;
    unsigned ul = __float_as_uint(lf);
    unsigned l16 = (ul + 0x7fffu + ((ul>>16)&1u)) >> 16;
    h[j] = (unsigned short)h16; lo[j] = (unsigned short)l16;
  }
  size_t o = (size_t)chunk*512 + lane*8;
  *(v8s*)(PH + o) = *(v8s*)h;
  *(v8s*)(PL + o) = *(v8s*)lo;
}

// ---------------- pack conv weight (O,2C) -> fragment-major bf16 hi/lo (2O x Kp) ------
__global__ void k_wpack(const float* __restrict__ Wm, unsigned short* __restrict__ PWH,
                        unsigned short* __restrict__ PWL, int C, int Kp, int O){
  int gid = blockIdx.x*256 + threadIdx.x;
  int nkc = Kp >> 4;
  int nchunk = (2*O/32)*nkc;
  if (gid >= nchunk*64) return;
  int lane = gid & 63;
  int chunk = gid >> 6;
  int jb = chunk / nkc, kc = chunk - jb*nkc;
  int j = jb*32 + (lane & 31);
  int k0 = kc*16 + ((lane>>5)<<3);
  unsigned short h[8], lo[8];
  #pragma unroll
  for (int t=0;t<8;t++){
    int k = k0 + t;
    float x = 0.f;
    if (k < C) x = (j < O) ? Wm[(size_t)j*2*C + k] : Wm[(size_t)(j-O)*2*C + C + k];
    unsigned u = __float_as_uint(x);
    unsigned h16 = (u + 0x7fffu + ((u>>16)&1u)) >> 16;
    float hf = __uint_as_float(h16 << 16);
    float lf = x - hf;
    unsigned ul = __float_as_uint(lf);
    unsigned l16 = (ul + 0x7fffu + ((ul>>16)&1u)) >> 16;
    h[t] = (unsigned short)h16; lo[t] = (unsigned short)l16;
  }
  size_t o = (size_t)chunk*512 + lane*8;
  *(v8s*)(PWH + o) = *(v8s*)h;
  *(v8s*)(PWL + o) = *(v8s*)lo;
}

// ---------------- fused distance+top20: MFMA tile in LDS, no global S ----------------
// Block = 512 threads (8 waves) per 32-row block. Each wave: 2 col-pairs (128 cols)
// via bf16x3 MFMA. Distances land in a 16-row x 1024-col LDS tile (two phases).
// After each phase every wave selects top-20 for 2 rows (tau prefilter + bitonic),
// using the row's own LDS as survivor scratch (values already in registers).
__global__ __launch_bounds__(512) void k_dtk(const unsigned short* __restrict__ PH,
    const unsigned short* __restrict__ PL, const float* __restrict__ xx,
    int* __restrict__ idx, int Kp){
  __shared__ float Sl[16][1024];          // 64 KB
  int wave = threadIdx.x >> 6;
  int l = threadIdx.x & 63;
  int rb = blockIdx.x;                    // rowblock 0..511
  int batch = rb >> 5;
  int nkc = Kp >> 4;
  const float* xxb = xx + (batch<<10);
  int rbase_local = (rb & 31)*32;

  v16f acc[4];
  #pragma unroll
  for (int i=0;i<4;i++){
    #pragma unroll
    for (int j=0;j<16;j++) acc[i][j] = 0.f;
  }
  #pragma unroll
  for (int pp=0; pp<2; pp++){
    int pair = wave*2 + pp;
    size_t a   = ((size_t)rb*nkc)*512 + l*8;
    size_t b0o = ((size_t)(batch*32 + 2*pair)*nkc)*512 + l*8;
    size_t b1o = b0o + (size_t)nkc*512;
    for (int kc=0; kc<nkc; kc++){
      v8s Ah  = *(const v8s*)(PH + a);
      v8s Al  = *(const v8s*)(PL + a);
      v8s B0h = *(const v8s*)(PH + b0o);
      v8s B0l = *(const v8s*)(PL + b0o);
      v8s B1h = *(const v8s*)(PH + b1o);
      v8s B1l = *(const v8s*)(PL + b1o);
      acc[2*pp]   = __builtin_amdgcn_mfma_f32_32x32x16_bf16(Ah, B0h, acc[2*pp],   0, 0, 0);
      acc[2*pp+1] = __builtin_amdgcn_mfma_f32_32x32x16_bf16(Ah, B1h, acc[2*pp+1], 0, 0, 0);
      acc[2*pp]   = __builtin_amdgcn_mfma_f32_32x32x16_bf16(Ah, B0l, acc[2*pp],   0, 0, 0);
      acc[2*pp+1] = __builtin_amdgcn_mfma_f32_32x32x16_bf16(Ah, B1l, acc[2*pp+1], 0, 0, 0);
      acc[2*pp]   = __builtin_amdgcn_mfma_f32_32x32x16_bf16(Al, B0h, acc[2*pp],   0, 0, 0);
      acc[2*pp+1] = __builtin_amdgcn_mfma_f32_32x32x16_bf16(Al, B1h, acc[2*pp+1], 0, 0, 0);
      a += 512; b0o += 512; b1o += 512;
    }
  }

  #pragma unroll
  for (int h=0; h<2; h++){
    // ---- write rows [16h,16h+16) of the tile into LDS with neg_d epilogue ----
    #pragma unroll
    for (int pp=0; pp<2; pp++){
      int pair = wave*2 + pp;
      int c0 = pair*64 + (l & 31), c1 = c0 + 32;
      float xc0 = xxb[c0], xc1 = xxb[c1];
      #pragma unroll
      for (int r = 0; r < 8; r++){
        int rr = h*8 + r;
        int rl = (rr&3) + (((rr>>2)&1)<<3) + ((l>>5)<<2);  // 0..15
        float xr = xxb[rbase_local + h*16 + rl];
        Sl[rl][c0] = 2.f*acc[2*pp][rr]   - xr - xc0;
        Sl[rl][c1] = 2.f*acc[2*pp+1][rr] - xr - xc1;
      }
    }
    __syncthreads();
    // ---- top-20 for 2 rows per wave ----
    #pragma unroll
    for (int i=0;i<2;i++){
      int rloc = wave*2 + i;
      int grow = rb*32 + h*16 + rloc;
      float vv[16];
      #pragma unroll
      for (int j=0;j<16;j++) vv[j] = Sl[rloc][l + 64*j];
      int out_base = grow*20;

      float lmax = vv[0];
      #pragma unroll
      for (int j=1;j<16;j++) lmax = fmaxf(lmax, vv[j]);

      float sv = lmax;
      #pragma unroll
      for (int k=2; k<=64; k<<=1){
        #pragma unroll
        for (int j=k>>1; j>0; j>>=1){
          float o = __shfl_xor(sv, j, 64);
          bool a2  = (l & k) == 0;
          bool bb = (l & j) == 0;
          sv = (a2 == bb) ? fminf(sv, o) : fmaxf(sv, o);
        }
      }
      float tau = __shfl(sv, 44, 64);

      int cnt = 0;
      #pragma unroll
      for (int j=0;j<16;j++) cnt += (vv[j] >= tau) ? 1 : 0;
      int inc = cnt;
      #pragma unroll
      for (int off=1; off<64; off<<=1){
        int t = __shfl_up(inc, off, 64);
        inc += (l >= off) ? t : 0;
      }
      int Ns = __shfl(inc, 63, 64);

      unsigned long long* sl = (unsigned long long*)&Sl[rloc][0];  // row scratch

      if (Ns <= 128){
        sl[l] = 0ull; sl[64+l] = 0ull;
        int slot = inc - cnt;
        #pragma unroll
        for (int j=0;j<16;j++){
          if (vv[j] >= tau){
            int m = l + 64*j;
            unsigned int mv = __float_as_uint(vv[j]);
            mv = (mv & 0x80000000u) ? ~mv : (mv | 0x80000000u);
            sl[slot] = ((unsigned long long)mv << 10) | (unsigned)(1023 - m);
            slot++;
          }
        }
        if (Ns <= 64){
          unsigned long long key = sl[l];
          #pragma unroll
          for (int k=2; k<=64; k<<=1){
            #pragma unroll
            for (int j=k>>1; j>0; j>>=1){
              unsigned long long o = __shfl_xor(key, j, 64);
              bool a2  = (l & k) == 0;
              bool bb = (l & j) == 0;
              unsigned long long mx = key > o ? key : o;
              unsigned long long mn = key > o ? o : key;
              key = (a2 == bb) ? mx : mn;
            }
          }
          if (l < 20) idx[out_base + l] = 1023 - (int)(key & 1023ull);
        } else {
          unsigned long long c0k = sl[l], c1k = sl[64+l];
          for (int kk=0; kk<20; kk++){
            unsigned long long m = c0k > c1k ? c0k : c1k;
            #pragma unroll
            for (int off=32; off>0; off>>=1){
              unsigned long long o = __shfl_xor(m, off, 64);
              m = o > m ? o : m;
            }
            c0k = (c0k == m) ? 0ull : c0k;
            c1k = (c1k == m) ? 0ull : c1k;
            if (l == 0) idx[out_base + kk] = 1023 - (int)(m & 1023ull);
          }
        }
      } else {
        for (int kk=0; kk<20; kk++){
          float bv = NEGINIT; int bi = 0x3fffffff;
          #pragma unroll
          for (int j=0;j<16;j++){
            int m = l + 64*j;
            if (vv[j] > bv){ bv = vv[j]; bi = m; }
          }
          #pragma unroll
          for (int off=32; off>0; off>>=1){
            float ov = __shfl_xor(bv, off, 64);
            int   oi = __shfl_xor(bi, off, 64);
            if (ov > bv || (ov == bv && oi < bi)){ bv = ov; bi = oi; }
          }
          #pragma unroll
          for (int j=0;j<16;j++)
            vv[j] = (l + 64*j == bi) ? REMOVED : vv[j];
          if (l == 0) idx[out_base + kk] = bi;
        }
      }
    }
    __syncthreads();
  }
}

// ---------------- Y = X . Wp^T via bf16x3-split MFMA, packed fragments --------------
__global__ __launch_bounds__(256) void k_ymf(const unsigned short* __restrict__ PH,
    const unsigned short* __restrict__ PL, const unsigned short* __restrict__ PWH,
    const unsigned short* __restrict__ PWL, float* __restrict__ Y, int Kp, int N, int npair){
  int w = threadIdx.x >> 6;
  int l = threadIdx.x & 63;
  int gw = blockIdx.x*4 + w;
  int mt = gw / npair;
  int pair = gw - mt*npair;
  int nkc = Kp >> 4;
  int jb0 = pair*2, jb1 = pair*2 + 1;
  size_t ao  = ((size_t)mt*nkc)*512 + l*8;
  size_t b0o = ((size_t)jb0*nkc)*512 + l*8;
  size_t b1o = ((size_t)jb1*nkc)*512 + l*8;
  v16f acc0, acc1;
  #pragma unroll
  for (int i=0;i<16;i++){ acc0[i] = 0.f; acc1[i] = 0.f; }
  for (int kc=0; kc<nkc; kc++){
    v8s Ah  = *(const v8s*)(PH + ao);
    v8s Al  = *(const v8s*)(PL + ao);
    v8s B0h = *(const v8s*)(PWH + b0o);
    v8s B0l = *(const v8s*)(PWL + b0o);
    v8s B1h = *(const v8s*)(PWH + b1o);
    v8s B1l = *(const v8s*)(PWL + b1o);
    acc0 = __builtin_amdgcn_mfma_f32_32x32x16_bf16(Ah, B0h, acc0, 0, 0, 0);
    acc1 = __builtin_amdgcn_mfma_f32_32x32x16_bf16(Ah, B1h, acc1, 0, 0, 0);
    acc0 = __builtin_amdgcn_mfma_f32_32x32x16_bf16(Ah, B0l, acc0, 0, 0, 0);
    acc1 = __builtin_amdgcn_mfma_f32_32x32x16_bf16(Ah, B1l, acc1, 0, 0, 0);
    acc0 = __builtin_amdgcn_mfma_f32_32x32x16_bf16(Al, B0h, acc0, 0, 0, 0);
    acc1 = __builtin_amdgcn_mfma_f32_32x32x16_bf16(Al, B1h, acc1, 0, 0, 0);
    ao += 512; b0o += 512; b1o += 512;
  }
  int rbase = mt*32;
  int c0 = pair*64 + (l & 31), c1 = c0 + 32;
  #pragma unroll
  for (int r=0;r<16;r++){
    int rl_ = (r&3) + ((r>>2)<<3) + ((l>>5)<<2);
    float* dst = Y + (size_t)(rbase + rl_)*N;
    dst[c0] = acc0[r];
    dst[c1] = acc1[r];
  }
}

// ---------------- thin NT GEMM (kept for the emb combine) ----------------
__global__ __launch_bounds__(256) void k_gthin(
    const float* __restrict__ Am, const float* __restrict__ Bm, float* __restrict__ Om,
    int K, int ldo, int wmode, const float* __restrict__ p1, const float* __restrict__ p2, int ep)
{
  __shared__ float As[64][33];
  __shared__ float Bs[64][68];
  int tid = threadIdx.x;
  int tx = tid & 15, ty = tid >> 4;
  int rbase = blockIdx.y*32, cbase = blockIdx.x*64;
  float acc[2][4];
  #pragma unroll
  for (int i=0;i<2;i++){ acc[i][0]=0.f; acc[i][1]=0.f; acc[i][2]=0.f; acc[i][3]=0.f; }

  for (int c0=0; c0<K; c0+=64){
    int cw = K - c0; if (cw > 64) cw = 64;
    #pragma unroll
    for (int p=0; p<2; p++){
      int idx = p*256 + tid;
      int kq = idx & 15, row = idx >> 4;
      const float* src = Am + (size_t)(rbase+row)*K + c0 + kq*4;
      float4 v = {0.f,0.f,0.f,0.f};
      if (kq*4 + 4 <= cw) v = *(const float4*)src;
      else {
        if (kq*4+0 < cw) v.x = src[0];
        if (kq*4+1 < cw) v.y = src[1];
        if (kq*4+2 < cw) v.z = src[2];
        if (kq*4+3 < cw) v.w = src[3];
      }
      As[kq*4+0][row]=v.x; As[kq*4+1][row]=v.y; As[kq*4+2][row]=v.z; As[kq*4+3][row]=v.w;
    }
    #pragma unroll
    for (int p=0; p<4; p++){
      int idx = p*256 + tid;
      int kq = idx & 15, col = idx >> 4;
      int j = cbase + col;
      const float* src = (wmode > 0)
          ? ((j < wmode) ? Bm + (size_t)j*2*K + c0 + kq*4
                         : Bm + (size_t)(j-wmode)*2*K + K + c0 + kq*4)
          : Bm + (size_t)j*K + c0 + kq*4;
      float4 v = {0.f,0.f,0.f,0.f};
      if (kq*4 + 4 <= cw) v = *(const float4*)src;
      else {
        if (kq*4+0 < cw) v.x = src[0];
        if (kq*4+1 < cw) v.y = src[1];
        if (kq*4+2 < cw) v.z = src[2];
        if (kq*4+3 < cw) v.w = src[3];
      }
      int swb = (kq & 14) << 1;
      int cs = col ^ swb;
      Bs[kq*4+0][cs]=v.x; Bs[kq*4+1][cs]=v.y; Bs[kq*4+2][cs]=v.z; Bs[kq*4+3][cs]=v.w;
    }
    __syncthreads();
    for (int k=0;k<cw;k++){
      int sw = ((k>>3)&7)<<2;
      float a0 = As[k][ty*2], a1 = As[k][ty*2+1];
      float b[4];
      *(float4*)b = *(const float4*)&Bs[k][(tx*4) ^ sw];
      acc[0][0]+=a0*b[0]; acc[0][1]+=a0*b[1]; acc[0][2]+=a0*b[2]; acc[0][3]+=a0*b[3];
      acc[1][0]+=a1*b[0]; acc[1][1]+=a1*b[1]; acc[1][2]+=a1*b[2]; acc[1][3]+=a1*b[3];
    }
    __syncthreads();
  }
  #pragma unroll
  for (int i=0;i<2;i++){
    int r = rbase + ty*2 + i;
    float o[4];
    #pragma unroll
    for (int j=0;j<4;j++){
      int cc = cbase + tx*4 + j;
      float v = acc[i][j];
      if (ep == 1) v = lrelu(p1[cc]*v*INV_SQRT1P + p2[cc]);
      o[j] = v;
    }
    *(float4*)(Om + (size_t)r*ldo + cbase + tx*4) = *(float4*)o;
  }
}

// ---------------- edge epilogue, multi-row blocks (256 threads) ----------------
__global__ __launch_bounds__(256) void k_edge(const float* __restrict__ Y, const int* __restrict__ idx,
    const float* __restrict__ g, const float* __restrict__ bias,
    float* __restrict__ out, int O, int ldo, int ooff){
  int rpb = 256/O;
  int rloc = threadIdx.x/O;
  int o = threadIdx.x - rloc*O;
  int row = blockIdx.x*rpb + rloc;
  int b = row >> 10;
  __shared__ int js[4][20];
  int nj = rpb*20;
  if (threadIdx.x < nj) js[threadIdx.x/20][threadIdx.x%20] = idx[(blockIdx.x*rpb)*20 + threadIdx.x];
  __syncthreads();
  int O2 = O*2;
  float y1c = Y[(size_t)row*O2 + o];
  float d   = Y[(size_t)row*O2 + O + o] - y1c;
  float sc  = g[o] * INV_SQRT1P;
  float bb  = bias[o];
  const float* Yb = Y + ((size_t)(b<<10))*O2;
  float best = -1e38f;
  #pragma unroll
  for (int k=0;k<20;k++){
    float f = sc * (Yb[(size_t)js[rloc][k]*O2 + o] + d) + bb;
    best = fmaxf(best, lrelu(f));
  }
  out[(size_t)row*ldo + ooff + o] = best;
}

// ---------------- attention (16 batches) ----------------
__global__ __launch_bounds__(1024) void k_mean(const float* __restrict__ emb, float* __restrict__ m){
  int b = blockIdx.x; int f = threadIdx.x & 127; int ny = threadIdx.x >> 7;
  const float* e = emb + ((size_t)(b<<10) + ny*128)*128 + f;
  float s = 0.f;
  for (int n=0;n<128;n++) s += e[n*128];
  __shared__ float red[8][128];
  red[ny][f] = s;
  __syncthreads();
  if (ny == 0){
    float t = 0.f;
    #pragma unroll
    for (int i=0;i<8;i++) t += red[i][f];
    m[b*128+f] = t * (1.0f/1024.0f);
  }
}

__global__ __launch_bounds__(128) void k_gc(const float* __restrict__ m, const float* __restrict__ att_w,
     float* __restrict__ gc){
  int b = blockIdx.x, g = threadIdx.x;
  __shared__ float mr[128];
  mr[g] = m[b*128+g];
  __syncthreads();
  float s = 0.f;
  for (int f=0; f<128; f++) s += mr[f]*att_w[f*128+g];
  gc[b*128+g] = tanhf(s);
}

__global__ __launch_bounds__(64) void k_sc(const float* __restrict__ emb, const float* __restrict__ gc,
     float* __restrict__ sc, float* __restrict__ attout){
  int row = blockIdx.x; int l = threadIdx.x; int b = row >> 10;
  const float* e  = emb + (size_t)row*128;
  const float* gb = gc + b*128;
  float p = e[l]*gb[l] + e[l+64]*gb[l+64];
  #pragma unroll
  for (int off=32; off>0; off>>=1) p += __shfl_xor(p, off, 64);
  if (l == 0){
    float s = 1.0f/(1.0f + expf(-p));
    sc[row] = s;
    attout[row] = s;
  }
}

__global__ __launch_bounds__(1024) void k_pool(const float* __restrict__ emb, const float* __restrict__ sc,
     float* __restrict__ ep){
  int b = blockIdx.x; int f = threadIdx.x & 127; int ny = threadIdx.x >> 7;
  const float* e  = emb + ((size_t)(b<<10) + ny*128)*128 + f;
  const float* sb = sc + (b<<10) + ny*128;
  float s = 0.f;
  for (int n=0;n<128;n++) s += e[n*128]*sb[n];
  __shared__ float red[8][128];
  red[ny][f] = s;
  __syncthreads();
  if (ny == 0){
    float t = 0.f;
    #pragma unroll
    for (int i=0;i<8;i++) t += red[i][f];
    ep[b*128+f] = t;
  }
}

// ---------------- tensor network scoring ----------------
__global__ __launch_bounds__(256) void k_tnet(const float* __restrict__ e1, const float* __restrict__ e2,
    const float* __restrict__ tn_w, const float* __restrict__ tn_wb, const float* __restrict__ tn_bias,
    float* __restrict__ tsout){
  int b = blockIdx.x; int t = threadIdx.x; int tt = t & 15; int fs = t >> 4;
  __shared__ float E1[128], E2[128], red[16][17];
  if (t < 128){ E1[t] = e1[b*128+t]; E2[t] = e2[b*128+t]; }
  __syncthreads();
  float acc = 0.f;
  for (int f = fs*8; f < fs*8+8; f++){
    const float* tw = tn_w + f*128*16 + tt;
    float partial = 0.f;
    for (int g=0; g<128; g++) partial += E2[g]*tw[g*16];
    acc += E1[f]*partial;
  }
  red[fs][tt] = acc;
  __syncthreads();
  if (t < 16){
    float s = 0.f;
    #pragma unroll
    for (int i=0;i<16;i++) s += red[i][t];
    float acc2 = 0.f;
    for (int c=0;c<128;c++) acc2 += tn_wb[t*256+c]*E1[c] + tn_wb[t*256+128+c]*E2[c];
    float v = s + acc2 + tn_bias[t];
    tsout[b*16+t] = v > 0.f ? v : 0.f;
  }
}

__global__ __launch_bounds__(128) void k_score2(const float* __restrict__ ts,
   const float* __restrict__ fc1_w, const float* __restrict__ fc1_b,
   const float* __restrict__ sc_w, const float* __restrict__ sc_b, float* __restrict__ out){
  int t = threadIdx.x; int b = t >> 4, i = t & 15;
  __shared__ float h2[8][17];
  float a = 0.f;
  #pragma unroll
  for (int k=0;k<16;k++) a += ts[b*16+k]*fc1_w[i*16+k];
  a += fc1_b[i];
  h2[b][i] = a > 0.f ? a : 0.f;
  __syncthreads();
  if (t < 8){
    float s = 0.f;
    #pragma unroll
    for (int k=0;k<16;k++) s += h2[t][k]*sc_w[k];
    s += sc_b[0];
    out[t] = 1.0f/(1.0f + expf(-s));
  }
}

extern "C" void kernel_launch(void* const* d_in, const int* in_sizes, int n_in,
                              void* d_out, int out_size, void* d_ws, size_t ws_size,
                              hipStream_t stream){
  const float* f1  = (const float*)d_in[0];
  const float* f2  = (const float*)d_in[1];
  const float* sw1 = (const float*)d_in[2];  const float* sg1 = (const float*)d_in[3];  const float* sb1 = (const float*)d_in[4];
  const float* fw1 = (const float*)d_in[5];  const float* fg1 = (const float*)d_in[6];  const float* fb1 = (const float*)d_in[7];
  const float* sw2 = (const float*)d_in[8];  const float* sg2 = (const float*)d_in[9];  const float* sb2 = (const float*)d_in[10];
  const float* fw2 = (const float*)d_in[11]; const float* fg2 = (const float*)d_in[12]; const float* fb2 = (const float*)d_in[13];
  const float* sw3 = (const float*)d_in[14]; const float* sg3 = (const float*)d_in[15]; const float* sb3 = (const float*)d_in[16];
  const float* fw3 = (const float*)d_in[17]; const float* fg3 = (const float*)d_in[18]; const float* fb3 = (const float*)d_in[19];
  const float* ew  = (const float*)d_in[20]; const float* eg  = (const float*)d_in[21]; const float* eb  = (const float*)d_in[22];
  const float* att_w   = (const float*)d_in[23];
  const float* tn_w    = (const float*)d_in[24];
  const float* tn_wb   = (const float*)d_in[25];
  const float* tn_bias = (const float*)d_in[26];
  const float* fc1_w   = (const float*)d_in[27];
  const float* fc1_b   = (const float*)d_in[28];
  const float* sc_w    = (const float*)d_in[29];
  const float* sc_b    = (const float*)d_in[30];

  float* W    = (float*)d_ws;
  float* T0   = W;                  // 2,097,152  (16384 x <=128)
  float* T1   = W + 2097152;        // 2,097,152
  float* X3S3 = W + 4194304;        // 4,194,304  (16384 x 256)
  float* EMB  = W + 8388608;        // 2,097,152  (16384 x 128)
  float* xx   = W + 10485760;       // 16384
  float* mb   = W + 10502144;       // 2048
  float* gcb  = W + 10504192;       // 2048
  float* scb  = W + 10506240;       // 16384
  float* ep   = W + 10522624;       // 2048
  float* tsb  = W + 10524672;       // 128
  int*   idxb = (int*)(W + 10524800);            // 327680 ints
  unsigned short* PH = (unsigned short*)(W + 10852480); // packed frags hi (1M floats)
  unsigned short* PL = (unsigned short*)(W + 11901056); // packed frags lo (1M floats)
  unsigned short* PWH = (unsigned short*)(W + 12949632); // packed weight hi (16K floats)
  unsigned short* PWL = (unsigned short*)(W + 12966016); // packed weight lo (16K floats)
  float* REG  = W + 12982400;       // Y (<= 4M floats)

  (void)ws_size;
  float* out = (float*)d_out;

  auto edge = [&](const float* xin, int C, int O,
                  const float* w, const float* g, const float* bb,
                  float* xout, int ldo, int ooff){
    int Kp = (C + 15) & ~15;
    int nkc = Kp >> 4;
    int npair = 2*O/64;
    k_xx<<<64, 256, 0, stream>>>(xin, xx, C);
    k_pack<<<(512*nkc*64+255)/256, 256, 0, stream>>>(xin, PH, PL, C, Kp);
    k_wpack<<<((2*O/32)*nkc*64+255)/256, 256, 0, stream>>>(w, PWH, PWL, C, Kp, O);
    k_dtk<<<512, 512, 0, stream>>>(PH, PL, xx, idxb, Kp);
    k_ymf<<<128*npair, 256, 0, stream>>>(PH, PL, PWH, PWL, REG, Kp, 2*O, npair);
    k_edge<<<16384/(256/O), 256, 0, stream>>>(REG, idxb, g, bb, xout, O, ldo, ooff);
  };

  // xyz path (both point clouds as batches 0-7 / 8-15)
  k_extract<<<(8*3*1024+255)/256, 256, 0, stream>>>(f1, T0, 0, 3, 0);
  k_extract<<<(8*3*1024+255)/256, 256, 0, stream>>>(f2, T0, 0, 3, 8);
  edge(T0, 3,   64, sw1, sg1, sb1, T1, 64, 0);
  edge(T1, 64,  64, sw2, sg2, sb2, T0, 64, 0);
  edge(T0, 64, 128, sw3, sg3, sb3, X3S3, 256, 0);    // x3 -> cols 0..127
  // sem path
  k_extract<<<(8*128*1024+255)/256, 256, 0, stream>>>(f1, T0, 3, 128, 0);
  k_extract<<<(8*128*1024+255)/256, 256, 0, stream>>>(f2, T0, 3, 128, 8);
  edge(T0, 128, 64, fw1, fg1, fb1, T1, 64, 0);
  edge(T1, 64,  64, fw2, fg2, fb2, T0, 64, 0);
  edge(T0, 64, 128, fw3, fg3, fb3, X3S3, 256, 128);  // s3 -> cols 128..255
  // combine: emb = lrelu(eg * (X3S3 @ ew^T)/sqrt(1+eps) + eb)
  k_gthin<<<dim3(2, 512, 1), 256, 0, stream>>>(X3S3, ew, EMB, 256, 128,
        0, eg, eb, 1);
  // attention over all 16 batches
  k_mean<<<16, 1024, 0, stream>>>(EMB, mb);
  k_gc<<<16, 128, 0, stream>>>(mb, att_w, gcb);
  k_sc<<<16384, 64, 0, stream>>>(EMB, gcb, scb, out + 8);
  k_pool<<<16, 1024, 0, stream>>>(EMB, scb, ep);

  k_tnet<<<8, 256, 0, stream>>>(ep, ep + 1024, tn_w, tn_wb, tn_bias, tsb);
  k_score2<<<1, 128, 0, stream>>>(tsb, fc1_w, fc1_b, sc_w, sc_b, out);
}